// Round 3
// baseline (71491.724 us; speedup 1.0000x reference)
//
#include <hip/hip_runtime.h>
#include <hip/hip_cooperative_groups.h>
#include <math.h>

namespace cg = cooperative_groups;

// Persistent cooperative decoder: 500 steps of (attention -> lstm0 -> lstm1),
// 256 blocks x 512 threads (1 block/CU guaranteed: 58.4 KB LDS < 64 KB,
// launch_bounds(512,2) -> <=256 VGPR), 3 grid.sync() per step.
// Fallback: if hipLaunchCooperativeKernel is rejected, run the round-1
// verified per-step kernel path (slower but correct).

#define NB 64
#define NS 500
#define NT 500

struct DecP {
    const float* ctx; const int* tgt;
    const float* Wih0; const float* Whh0;
    const float* Wih1; const float* Whh1;
    const float* bih1; const float* bhh1;
    const float* Wl;   const float* bl;
    float* out;
    float* h1a; float* h1b; float* h2a; float* h2b;
    float* c1;  float* c2;  float* E;
    float* pm;  float* pl;  float* pacc; float* algn;
    int* idx;   int* cnt;
};

// ---------------------------------------------------------------- init
__global__ __launch_bounds__(256) void init_kernel(
    const float* __restrict__ h1_0, const float* __restrict__ c1_0,
    const float* __restrict__ h2_0, const float* __restrict__ c2_0,
    const int* __restrict__ tgt,
    float* __restrict__ h1a, float* __restrict__ c1,
    float* __restrict__ h2a, float* __restrict__ c2,
    int* __restrict__ idx, int* __restrict__ cnt)
{
    int gid = blockIdx.x * 256 + threadIdx.x;   // grid 128 -> 32768
    h1a[gid] = h1_0[gid];
    c1[gid]  = c1_0[gid];
    h2a[gid] = h2_0[gid];
    c2[gid]  = c2_0[gid];
    if (gid < NB) { idx[gid] = tgt[gid * NT]; cnt[gid] = 0; }
}

// ------------------------------------------------- E = emb @ W_ih0[:, :512].T + b_ih0 + b_hh0
__global__ __launch_bounds__(256) void eproj_kernel(
    const float* __restrict__ emb, const float* __restrict__ Wih0,
    const float* __restrict__ bih0, const float* __restrict__ bhh0,
    float* __restrict__ E)
{
    int gid = blockIdx.x * 256 + threadIdx.x;   // grid 24 -> 6144 = 3*2048
    int v = gid >> 11, g = gid & 2047;
    const float4* wr = (const float4*)(Wih0 + (size_t)g * 1536);
    const float4* er = (const float4*)(emb + v * 512);
    float s = bih0[g] + bhh0[g];
    #pragma unroll 4
    for (int i = 0; i < 128; ++i) {
        float4 w = wr[i], e = er[i];
        s += w.x*e.x + w.y*e.y + w.z*e.z + w.w*e.w;
    }
    E[v * 2048 + g] = s;
}

// ---------------------------------------------------------------- persistent decoder
__global__ __launch_bounds__(512, 2) void decoder_persist(DecP P)
{
    cg::grid_group grid = cg::this_grid();
    __shared__ float smem[14592];   // 58368 B
    __shared__ float wm[8], wls[8];
    __shared__ float lg[3];
    __shared__ int   is_last;
    __shared__ int   idx_s[8];

    const int tid  = threadIdx.x;
    const int blk  = blockIdx.x;
    const int lane = tid & 63, wave = tid >> 6;

    const int b_at = blk & 63, ch = blk >> 6;   // attention: 64 b x 4 chunks
    const int jc2  = blk & 31, bg = blk >> 5;   // gemm: 32 j-chunks(16j) x 8 b-groups

    float* h1i = P.h1a; float* h1o = P.h1b;
    float* h2i = P.h2a; float* h2o = P.h2b;

    #pragma unroll 1
    for (int t = 0; t < NT; ++t) {
        // ================= Phase A: logits(t-1) + attention =================
        {
            float* q_s  = smem;          // 512
            float* wacc = smem + 512;    // 8*1024
            q_s[tid] = h2i[b_at * 512 + tid];
            __syncthreads();

            if (ch == 0 && t > 0) {      // block-uniform branch
                if (tid < 192) {
                    int v = tid >> 6;
                    float p = 0.f;
                    #pragma unroll
                    for (int j = 0; j < 8; ++j)
                        p += q_s[lane * 8 + j] * P.Wl[v * 512 + lane * 8 + j];
                    #pragma unroll
                    for (int off = 32; off; off >>= 1) p += __shfl_xor(p, off);
                    if (lane == 0) lg[v] = p + P.bl[v];
                }
                __syncthreads();
                if (tid == 0) {
                    float m = fmaxf(lg[0], fmaxf(lg[1], lg[2]));
                    float e0 = expf(lg[0] - m), e1 = expf(lg[1] - m), e2 = expf(lg[2] - m);
                    float ls = logf(e0 + e1 + e2);
                    float* o = P.out + ((size_t)b_at * NT + (t - 1)) * 3;
                    o[0] = lg[0] - m - ls; o[1] = lg[1] - m - ls; o[2] = lg[2] - m - ls;
                    int am = 0;
                    if (lg[1] > lg[am]) am = 1;
                    if (lg[2] > lg[am]) am = 2;
                    P.idx[b_at] = am;
                }
            }

            const int s0 = ch * 125;
            const int se = s0 + 125;               // 4*125 = 500 exact
            int sA = s0 + wave * 16;
            int sB = sA + 16; if (sB > se) sB = se;
            float4 q0 = ((const float4*)q_s)[lane];
            float4 q1 = ((const float4*)q_s)[64 + lane];
            float m = -INFINITY, l = 0.f;
            float4 a0 = {0,0,0,0}, a1 = {0,0,0,0}, a2 = {0,0,0,0}, a3 = {0,0,0,0};

            for (int s = sA; s < sB; s += 2) {
                const int two = (s + 1 < sB);
                const float4* r0 = (const float4*)(P.ctx + ((size_t)b_at * NS + s) * 1024);
                const float4* r1 = (const float4*)(P.ctx + ((size_t)b_at * NS + (two ? s + 1 : s)) * 1024);
                float4 u0 = r0[lane], u1 = r0[64+lane], u2 = r0[128+lane], u3 = r0[192+lane];
                float4 v0 = r1[lane], v1 = r1[64+lane], v2 = r1[128+lane], v3 = r1[192+lane];
                float p0 = u0.x*q0.x + u0.y*q0.y + u0.z*q0.z + u0.w*q0.w
                         + u1.x*q1.x + u1.y*q1.y + u1.z*q1.z + u1.w*q1.w
                         + u2.x*q0.x + u2.y*q0.y + u2.z*q0.z + u2.w*q0.w
                         + u3.x*q1.x + u3.y*q1.y + u3.z*q1.z + u3.w*q1.w;
                float p1 = v0.x*q0.x + v0.y*q0.y + v0.z*q0.z + v0.w*q0.w
                         + v1.x*q1.x + v1.y*q1.y + v1.z*q1.z + v1.w*q1.w
                         + v2.x*q0.x + v2.y*q0.y + v2.z*q0.z + v2.w*q0.w
                         + v3.x*q1.x + v3.y*q1.y + v3.z*q1.z + v3.w*q1.w;
                #pragma unroll
                for (int off = 32; off; off >>= 1) {
                    p0 += __shfl_xor(p0, off);
                    p1 += __shfl_xor(p1, off);
                }
                if (!two) p1 = -INFINITY;
                float mn = fmaxf(m, fmaxf(p0, p1));
                float al = expf(m - mn);    // first iter: exp(-inf)=0
                float w0 = expf(p0 - mn);
                float w1 = expf(p1 - mn);   // !two: exp(-inf)=0
                l = l * al + w0 + w1;
                a0.x = fmaf(w1, v0.x, fmaf(w0, u0.x, a0.x*al));
                a0.y = fmaf(w1, v0.y, fmaf(w0, u0.y, a0.y*al));
                a0.z = fmaf(w1, v0.z, fmaf(w0, u0.z, a0.z*al));
                a0.w = fmaf(w1, v0.w, fmaf(w0, u0.w, a0.w*al));
                a1.x = fmaf(w1, v1.x, fmaf(w0, u1.x, a1.x*al));
                a1.y = fmaf(w1, v1.y, fmaf(w0, u1.y, a1.y*al));
                a1.z = fmaf(w1, v1.z, fmaf(w0, u1.z, a1.z*al));
                a1.w = fmaf(w1, v1.w, fmaf(w0, u1.w, a1.w*al));
                a2.x = fmaf(w1, v2.x, fmaf(w0, u2.x, a2.x*al));
                a2.y = fmaf(w1, v2.y, fmaf(w0, u2.y, a2.y*al));
                a2.z = fmaf(w1, v2.z, fmaf(w0, u2.z, a2.z*al));
                a2.w = fmaf(w1, v2.w, fmaf(w0, u2.w, a2.w*al));
                a3.x = fmaf(w1, v3.x, fmaf(w0, u3.x, a3.x*al));
                a3.y = fmaf(w1, v3.y, fmaf(w0, u3.y, a3.y*al));
                a3.z = fmaf(w1, v3.z, fmaf(w0, u3.z, a3.z*al));
                a3.w = fmaf(w1, v3.w, fmaf(w0, u3.w, a3.w*al));
                m = mn;
            }
            ((float4*)wacc)[wave*256 + lane]       = a0;
            ((float4*)wacc)[wave*256 + 64 + lane]  = a1;
            ((float4*)wacc)[wave*256 + 128 + lane] = a2;
            ((float4*)wacc)[wave*256 + 192 + lane] = a3;
            if (lane == 0) { wm[wave] = m; wls[wave] = l; }
            __syncthreads();
            {   // combine 8 wave partials -> chunk partial (each thread 2 d's)
                float M = wm[0];
                #pragma unroll
                for (int w = 1; w < 8; ++w) M = fmaxf(M, wm[w]);
                float e[8]; float L = 0.f;
                #pragma unroll
                for (int w = 0; w < 8; ++w) { e[w] = expf(wm[w] - M); L += e[w] * wls[w]; }
                int d2 = tid * 2;
                float rx = 0.f, ry = 0.f;
                #pragma unroll
                for (int w = 0; w < 8; ++w) {
                    float2 x = *(float2*)&wacc[w*1024 + d2];
                    rx = fmaf(e[w], x.x, rx); ry = fmaf(e[w], x.y, ry);
                }
                *(float2*)&P.pacc[((size_t)(b_at*4 + ch))*1024 + d2] = make_float2(rx, ry);
                if (tid == 0) { P.pm[b_at*4 + ch] = M; P.pl[b_at*4 + ch] = L; }
            }
            __syncthreads();
            if (tid == 0) {
                __threadfence();
                int old = __hip_atomic_fetch_add(P.cnt + b_at, 1, __ATOMIC_ACQ_REL,
                                                 __HIP_MEMORY_SCOPE_AGENT);
                is_last = (old == 4*t + 3) ? 1 : 0;     // monotone counter
            }
            __syncthreads();
            if (is_last) {      // combine 4 chunks -> align[b]
                float M = -INFINITY;
                #pragma unroll
                for (int k = 0; k < 4; ++k) M = fmaxf(M, P.pm[b_at*4 + k]);
                float e[4]; float L = 0.f;
                #pragma unroll
                for (int k = 0; k < 4; ++k) { e[k] = expf(P.pm[b_at*4 + k] - M); L += e[k] * P.pl[b_at*4 + k]; }
                float invL = 1.f / L;
                int d2 = tid * 2;
                float rx = 0.f, ry = 0.f;
                #pragma unroll
                for (int k = 0; k < 4; ++k) {
                    float2 x = *(float2*)&P.pacc[((size_t)(b_at*4 + k))*1024 + d2];
                    rx = fmaf(e[k], x.x, rx); ry = fmaf(e[k], x.y, ry);
                }
                *(float2*)&P.algn[b_at*1024 + d2] = make_float2(rx*invL, ry*invL);
            }
        }
        grid.sync();
        // ================= Phase B: lstm0 -> h1 =================
        {
            float* x0    = smem;           // 8 b x 1536 k  [b][k]
            float* gred2 = smem + 12288;   // 8 rg x 8 kgrp x 32
            float* gred  = smem + 14336;   // 256
            if (tid < 8) idx_s[tid] = P.idx[bg*8 + tid];
            #pragma unroll
            for (int j = 0; j < 6; ++j) {
                int i4 = tid + j*512;               // 0..3071 float4s
                int bb = i4 / 384, r = i4 - bb*384;
                int b = bg*8 + bb;
                float4 v = (r < 256) ? ((const float4*)(P.algn + b*1024))[r]
                                     : ((const float4*)(h1i + b*512))[r - 256];
                ((float4*)x0)[i4] = v;
            }
            __syncthreads();
            const int rg = wave;
            const int g = rg >> 1, qq = (rg & 1) * 4;
            #pragma unroll 1
            for (int p = 0; p < 2; ++p) {
                const int jc = jc2*2 + p;
                const int row0 = g*512 + jc*8 + qq;     // rows row0..row0+3
                float af[32];
                #pragma unroll
                for (int q = 0; q < 32; ++q) af[q] = 0.f;
                #pragma unroll
                for (int i = 0; i < 6; ++i) {
                    int k = i*256 + lane*4;
                    float4 w0, w1, w2, w3;
                    if (i < 4) {
                        const float* wb = P.Wih0 + (size_t)row0*1536 + 512 + k;
                        w0 = *(const float4*)(wb);
                        w1 = *(const float4*)(wb + 1536);
                        w2 = *(const float4*)(wb + 3072);
                        w3 = *(const float4*)(wb + 4608);
                    } else {
                        const float* wb = P.Whh0 + (size_t)row0*512 + (k - 1024);
                        w0 = *(const float4*)(wb);
                        w1 = *(const float4*)(wb + 512);
                        w2 = *(const float4*)(wb + 1024);
                        w3 = *(const float4*)(wb + 1536);
                    }
                    #pragma unroll
                    for (int bb = 0; bb < 8; ++bb) {
                        float4 x = *(const float4*)&x0[bb*1536 + k];
                        af[0*8+bb] = fmaf(w0.w, x.w, fmaf(w0.z, x.z, fmaf(w0.y, x.y, fmaf(w0.x, x.x, af[0*8+bb]))));
                        af[1*8+bb] = fmaf(w1.w, x.w, fmaf(w1.z, x.z, fmaf(w1.y, x.y, fmaf(w1.x, x.x, af[1*8+bb]))));
                        af[2*8+bb] = fmaf(w2.w, x.w, fmaf(w2.z, x.z, fmaf(w2.y, x.y, fmaf(w2.x, x.x, af[2*8+bb]))));
                        af[3*8+bb] = fmaf(w3.w, x.w, fmaf(w3.z, x.z, fmaf(w3.y, x.y, fmaf(w3.x, x.x, af[3*8+bb]))));
                    }
                }
                #pragma unroll
                for (int mm = 1; mm <= 4; mm <<= 1) {
                    #pragma unroll
                    for (int q = 0; q < 32; ++q) af[q] += __shfl_xor(af[q], mm);
                }
                if ((lane & 7) == 0) {
                    const int kg = lane >> 3;
                    float* gdst = gred2 + rg*256 + kg*32;
                    #pragma unroll
                    for (int q = 0; q < 8; ++q)
                        *(float4*)(gdst + q*4) = make_float4(af[q*4], af[q*4+1], af[q*4+2], af[q*4+3]);
                }
                __syncthreads();
                if (tid < 256) {
                    int rb = tid >> 3, bb = tid & 7;
                    int rg2 = rb >> 2, rr2 = rb & 3;
                    float s = 0.f;
                    #pragma unroll
                    for (int kg = 0; kg < 8; ++kg) s += gred2[rg2*256 + kg*32 + rr2*8 + bb];
                    gred[tid] = s;   // gred[(g*8+jj)*8+bb]
                }
                __syncthreads();
                if (tid < 64) {
                    int jj = tid >> 3, bb = tid & 7;
                    int j = jc*8 + jj, b = bg*8 + bb;
                    float gv[4];
                    #pragma unroll
                    for (int gg = 0; gg < 4; ++gg)
                        gv[gg] = gred[(gg*8 + jj)*8 + bb] + P.E[idx_s[bb]*2048 + gg*512 + j];
                    float ig = 1.f / (1.f + expf(-gv[0]));
                    float fg = 1.f / (1.f + expf(-gv[1]));
                    float g2 = tanhf(gv[2]);
                    float og = 1.f / (1.f + expf(-gv[3]));
                    float cn = fg * P.c1[b*512 + j] + ig * g2;
                    P.c1[b*512 + j] = cn;
                    h1o[b*512 + j] = og * tanhf(cn);
                }
            }
        }
        grid.sync();
        // ================= Phase C: lstm1 -> h2 =================
        {
            float* x1    = smem;           // 8 b x 1024 k  [b][k]
            float* gred2 = smem + 12288;
            float* gred  = smem + 14336;
            #pragma unroll
            for (int j = 0; j < 4; ++j) {
                int i4 = tid + j*512;               // 0..2047 float4s
                int bb = i4 >> 8, r = i4 & 255;
                int b = bg*8 + bb;
                float4 v = (r < 128) ? ((const float4*)(h1o + b*512))[r]
                                     : ((const float4*)(h2i + b*512))[r - 128];
                ((float4*)x1)[i4] = v;
            }
            __syncthreads();
            const int rg = wave;
            const int g = rg >> 1, qq = (rg & 1) * 4;
            #pragma unroll 1
            for (int p = 0; p < 2; ++p) {
                const int jc = jc2*2 + p;
                const int row0 = g*512 + jc*8 + qq;
                float af[32];
                #pragma unroll
                for (int q = 0; q < 32; ++q) af[q] = 0.f;
                #pragma unroll
                for (int i = 0; i < 4; ++i) {
                    int k = i*256 + lane*4;
                    float4 w0, w1, w2, w3;
                    if (i < 2) {
                        const float* wb = P.Wih1 + (size_t)row0*512 + k;
                        w0 = *(const float4*)(wb);
                        w1 = *(const float4*)(wb + 512);
                        w2 = *(const float4*)(wb + 1024);
                        w3 = *(const float4*)(wb + 1536);
                    } else {
                        const float* wb = P.Whh1 + (size_t)row0*512 + (k - 512);
                        w0 = *(const float4*)(wb);
                        w1 = *(const float4*)(wb + 512);
                        w2 = *(const float4*)(wb + 1024);
                        w3 = *(const float4*)(wb + 1536);
                    }
                    #pragma unroll
                    for (int bb = 0; bb < 8; ++bb) {
                        float4 x = *(const float4*)&x1[bb*1024 + k];
                        af[0*8+bb] = fmaf(w0.w, x.w, fmaf(w0.z, x.z, fmaf(w0.y, x.y, fmaf(w0.x, x.x, af[0*8+bb]))));
                        af[1*8+bb] = fmaf(w1.w, x.w, fmaf(w1.z, x.z, fmaf(w1.y, x.y, fmaf(w1.x, x.x, af[1*8+bb]))));
                        af[2*8+bb] = fmaf(w2.w, x.w, fmaf(w2.z, x.z, fmaf(w2.y, x.y, fmaf(w2.x, x.x, af[2*8+bb]))));
                        af[3*8+bb] = fmaf(w3.w, x.w, fmaf(w3.z, x.z, fmaf(w3.y, x.y, fmaf(w3.x, x.x, af[3*8+bb]))));
                    }
                }
                #pragma unroll
                for (int mm = 1; mm <= 4; mm <<= 1) {
                    #pragma unroll
                    for (int q = 0; q < 32; ++q) af[q] += __shfl_xor(af[q], mm);
                }
                if ((lane & 7) == 0) {
                    const int kg = lane >> 3;
                    float* gdst = gred2 + rg*256 + kg*32;
                    #pragma unroll
                    for (int q = 0; q < 8; ++q)
                        *(float4*)(gdst + q*4) = make_float4(af[q*4], af[q*4+1], af[q*4+2], af[q*4+3]);
                }
                __syncthreads();
                if (tid < 256) {
                    int rb = tid >> 3, bb = tid & 7;
                    int rg2 = rb >> 2, rr2 = rb & 3;
                    float s = 0.f;
                    #pragma unroll
                    for (int kg = 0; kg < 8; ++kg) s += gred2[rg2*256 + kg*32 + rr2*8 + bb];
                    gred[tid] = s;
                }
                __syncthreads();
                if (tid < 64) {
                    int jj = tid >> 3, bb = tid & 7;
                    int j = jc*8 + jj, b = bg*8 + bb;
                    float gv[4];
                    #pragma unroll
                    for (int gg = 0; gg < 4; ++gg)
                        gv[gg] = gred[(gg*8 + jj)*8 + bb] + P.bih1[gg*512 + j] + P.bhh1[gg*512 + j];
                    float ig = 1.f / (1.f + expf(-gv[0]));
                    float fg = 1.f / (1.f + expf(-gv[1]));
                    float g2 = tanhf(gv[2]);
                    float og = 1.f / (1.f + expf(-gv[3]));
                    float cn = fg * P.c2[b*512 + j] + ig * g2;
                    P.c2[b*512 + j] = cn;
                    h2o[b*512 + j] = og * tanhf(cn);
                }
            }
        }
        grid.sync();
        // swap state buffers
        float* tsw;
        tsw = h1i; h1i = h1o; h1o = tsw;
        tsw = h2i; h2i = h2o; h2o = tsw;
    }
    // ================= tail: logits(499) + target copy =================
    if (blk < NB) {
        const int b = blk;
        float* q_s = smem;
        q_s[tid] = h2i[b*512 + tid];
        __syncthreads();
        if (tid < 192) {
            int v = tid >> 6;
            float p = 0.f;
            #pragma unroll
            for (int j = 0; j < 8; ++j)
                p += q_s[lane*8 + j] * P.Wl[v*512 + lane*8 + j];
            #pragma unroll
            for (int off = 32; off; off >>= 1) p += __shfl_xor(p, off);
            if (lane == 0) lg[v] = p + P.bl[v];
        }
        __syncthreads();
        if (tid == 0) {
            float m = fmaxf(lg[0], fmaxf(lg[1], lg[2]));
            float e0 = expf(lg[0]-m), e1 = expf(lg[1]-m), e2 = expf(lg[2]-m);
            float ls = logf(e0 + e1 + e2);
            float* o = P.out + ((size_t)b*NT + (NT-1))*3;
            o[0] = lg[0]-m-ls; o[1] = lg[1]-m-ls; o[2] = lg[2]-m-ls;
        }
        for (int i = tid; i < NT; i += 512)
            P.out[NB*NT*3 + b*NT + i] = (float)P.tgt[b*NT + i];
    }
}

// ================================================================ fallback path
// Round-1 verified per-step kernels (used only if cooperative launch is rejected).
#define NCHF 8
#define CHSF 63

__global__ __launch_bounds__(256) void attn_fb(
    const float* __restrict__ ctx, const float* __restrict__ h2_in,
    const float* __restrict__ Wl, const float* __restrict__ bl,
    float* __restrict__ pm, float* __restrict__ pl, float* __restrict__ pacc,
    float* __restrict__ align_g, int* __restrict__ cnt, int* __restrict__ idx,
    float* __restrict__ out, int t)
{
    __shared__ alignas(16) float q_s[512];
    __shared__ alignas(16) float wacc[4 * 1024];
    __shared__ float wm[4], wl_s[4];
    __shared__ float lg[3];
    __shared__ int is_last;
    const int tid = threadIdx.x;
    const int ch = blockIdx.x, b = blockIdx.y;

    q_s[tid]       = h2_in[b * 512 + tid];
    q_s[tid + 256] = h2_in[b * 512 + 256 + tid];
    __syncthreads();

    if (ch == 0 && t > 0) {
        if (tid < 192) {
            int v = tid >> 6, lane = tid & 63;
            float p = 0.f;
            #pragma unroll
            for (int j = 0; j < 8; ++j)
                p += q_s[lane * 8 + j] * Wl[v * 512 + lane * 8 + j];
            for (int off = 32; off; off >>= 1) p += __shfl_xor(p, off);
            if (lane == 0) lg[v] = p + bl[v];
        }
        __syncthreads();
        if (tid == 0) {
            float m = fmaxf(lg[0], fmaxf(lg[1], lg[2]));
            float e0 = expf(lg[0] - m), e1 = expf(lg[1] - m), e2 = expf(lg[2] - m);
            float ls = logf(e0 + e1 + e2);
            float* o = out + ((size_t)b * NT + (t - 1)) * 3;
            o[0] = lg[0] - m - ls; o[1] = lg[1] - m - ls; o[2] = lg[2] - m - ls;
            int am = 0;
            if (lg[1] > lg[am]) am = 1;
            if (lg[2] > lg[am]) am = 2;
            idx[b] = am;
        }
    }

    const int lane = tid & 63, wave = tid >> 6;
    const int s0 = ch * CHSF;
    const int s1 = (s0 + CHSF < NS) ? s0 + CHSF : NS;
    float4 q0 = ((const float4*)q_s)[lane];
    float4 q1 = ((const float4*)q_s)[64 + lane];
    float m = -INFINITY, l = 0.f;
    float4 a0 = {0,0,0,0}, a1 = {0,0,0,0}, a2 = {0,0,0,0}, a3 = {0,0,0,0};

    for (int s = s0 + wave; s < s1; s += 4) {
        const float4* crow = (const float4*)(ctx + ((size_t)b * NS + s) * 1024);
        float4 v0 = crow[lane], v1 = crow[64 + lane], v2 = crow[128 + lane], v3 = crow[192 + lane];
        float p = v0.x*q0.x + v0.y*q0.y + v0.z*q0.z + v0.w*q0.w
                + v1.x*q1.x + v1.y*q1.y + v1.z*q1.z + v1.w*q1.w
                + v2.x*q0.x + v2.y*q0.y + v2.z*q0.z + v2.w*q0.w
                + v3.x*q1.x + v3.y*q1.y + v3.z*q1.z + v3.w*q1.w;
        for (int off = 32; off; off >>= 1) p += __shfl_xor(p, off);
        float mn = fmaxf(m, p);
        float al = expf(m - mn);
        float w  = expf(p - mn);
        l = l * al + w;
        a0.x = a0.x*al + w*v0.x; a0.y = a0.y*al + w*v0.y; a0.z = a0.z*al + w*v0.z; a0.w = a0.w*al + w*v0.w;
        a1.x = a1.x*al + w*v1.x; a1.y = a1.y*al + w*v1.y; a1.z = a1.z*al + w*v1.z; a1.w = a1.w*al + w*v1.w;
        a2.x = a2.x*al + w*v2.x; a2.y = a2.y*al + w*v2.y; a2.z = a2.z*al + w*v2.z; a2.w = a2.w*al + w*v2.w;
        a3.x = a3.x*al + w*v3.x; a3.y = a3.y*al + w*v3.y; a3.z = a3.z*al + w*v3.z; a3.w = a3.w*al + w*v3.w;
        m = mn;
    }
    ((float4*)wacc)[wave * 256 + lane]       = a0;
    ((float4*)wacc)[wave * 256 + 64 + lane]  = a1;
    ((float4*)wacc)[wave * 256 + 128 + lane] = a2;
    ((float4*)wacc)[wave * 256 + 192 + lane] = a3;
    if (lane == 0) { wm[wave] = m; wl_s[wave] = l; }
    __syncthreads();
    {
        float M = fmaxf(fmaxf(wm[0], wm[1]), fmaxf(wm[2], wm[3]));
        float e0 = expf(wm[0]-M), e1 = expf(wm[1]-M), e2 = expf(wm[2]-M), e3 = expf(wm[3]-M);
        float L = e0*wl_s[0] + e1*wl_s[1] + e2*wl_s[2] + e3*wl_s[3];
        const float4* w4 = (const float4*)wacc;
        float4 x0 = w4[tid], x1 = w4[256 + tid], x2 = w4[512 + tid], x3 = w4[768 + tid];
        float4 r;
        r.x = e0*x0.x + e1*x1.x + e2*x2.x + e3*x3.x;
        r.y = e0*x0.y + e1*x1.y + e2*x2.y + e3*x3.y;
        r.z = e0*x0.z + e1*x1.z + e2*x2.z + e3*x3.z;
        r.w = e0*x0.w + e1*x1.w + e2*x2.w + e3*x3.w;
        ((float4*)pacc)[(b * NCHF + ch) * 256 + tid] = r;
        if (tid == 0) { pm[b * NCHF + ch] = M; pl[b * NCHF + ch] = L; }
    }
    __syncthreads();
    if (tid == 0) {
        __threadfence();
        int old = __hip_atomic_fetch_add(cnt + b, 1, __ATOMIC_ACQ_REL, __HIP_MEMORY_SCOPE_AGENT);
        is_last = (old == NCHF * t + (NCHF - 1)) ? 1 : 0;
    }
    __syncthreads();
    if (is_last) {
        float M = -INFINITY;
        #pragma unroll
        for (int k = 0; k < NCHF; ++k) M = fmaxf(M, pm[b * NCHF + k]);
        float e[NCHF]; float L = 0.f;
        #pragma unroll
        for (int k = 0; k < NCHF; ++k) { e[k] = expf(pm[b * NCHF + k] - M); L += e[k] * pl[b * NCHF + k]; }
        float invL = 1.f / L;
        const float4* p4 = (const float4*)pacc;
        float4 r = {0,0,0,0};
        #pragma unroll
        for (int k = 0; k < NCHF; ++k) {
            float4 x = p4[(b * NCHF + k) * 256 + tid];
            r.x += e[k]*x.x; r.y += e[k]*x.y; r.z += e[k]*x.z; r.w += e[k]*x.w;
        }
        r.x *= invL; r.y *= invL; r.z *= invL; r.w *= invL;
        ((float4*)align_g)[b * 256 + tid] = r;
    }
}

__global__ __launch_bounds__(256) void lstm0_fb(
    const float* __restrict__ align_g, const float* __restrict__ h1_in,
    float* __restrict__ c1, const float* __restrict__ E,
    const int* __restrict__ idx, const float* __restrict__ Wih0,
    const float* __restrict__ Whh0, float* __restrict__ h1_out)
{
    __shared__ alignas(16) float smem[1536 * 10];
    __shared__ int idx_s[8];
    const int tid = threadIdx.x;
    const int jc = blockIdx.x;
    const int b0 = blockIdx.y << 3;
    {
        const int dc = tid & 31, bb = tid >> 5;
        const float* arow = align_g + (size_t)(b0 + bb) * 1024;
        const float* hrow = h1_in + (size_t)(b0 + bb) * 512;
        #pragma unroll 4
        for (int i = 0; i < 32; ++i) { int d = dc + (i << 5); smem[d * 10 + bb] = arow[d]; }
        #pragma unroll 4
        for (int i = 0; i < 16; ++i) { int d = dc + (i << 5); smem[(1024 + d) * 10 + bb] = hrow[d]; }
        if (tid < 8) idx_s[tid] = idx[b0 + tid];
    }
    __syncthreads();
    const int lane = tid & 63, wave = tid >> 6;
    const int sl = lane & 15;
    const int rt = (wave << 2) | (lane >> 4);
    const int g0r = ((rt      ) >> 3) * 512 + (jc << 3) + (rt & 7);
    const int g1r = ((rt + 16 ) >> 3) * 512 + (jc << 3) + (rt & 7);
    const float* wa0 = Wih0 + (size_t)g0r * 1536 + 512;
    const float* wa1 = Wih0 + (size_t)g1r * 1536 + 512;
    const float* wh0 = Whh0 + (size_t)g0r * 512;
    const float* wh1 = Whh0 + (size_t)g1r * 512;
    float acc[2][8];
    #pragma unroll
    for (int r = 0; r < 2; ++r)
        #pragma unroll
        for (int q = 0; q < 8; ++q) acc[r][q] = 0.f;
    #pragma unroll 2
    for (int i = 0; i < 64; ++i) {
        int d = sl + (i << 4);
        float w0 = wa0[d], w1 = wa1[d];
        const float2* a2 = (const float2*)(smem + d * 10);
        float2 x0 = a2[0], x1 = a2[1], x2 = a2[2], x3 = a2[3];
        acc[0][0] = fmaf(w0, x0.x, acc[0][0]); acc[1][0] = fmaf(w1, x0.x, acc[1][0]);
        acc[0][1] = fmaf(w0, x0.y, acc[0][1]); acc[1][1] = fmaf(w1, x0.y, acc[1][1]);
        acc[0][2] = fmaf(w0, x1.x, acc[0][2]); acc[1][2] = fmaf(w1, x1.x, acc[1][2]);
        acc[0][3] = fmaf(w0, x1.y, acc[0][3]); acc[1][3] = fmaf(w1, x1.y, acc[1][3]);
        acc[0][4] = fmaf(w0, x2.x, acc[0][4]); acc[1][4] = fmaf(w1, x2.x, acc[1][4]);
        acc[0][5] = fmaf(w0, x2.y, acc[0][5]); acc[1][5] = fmaf(w1, x2.y, acc[1][5]);
        acc[0][6] = fmaf(w0, x3.x, acc[0][6]); acc[1][6] = fmaf(w1, x3.x, acc[1][6]);
        acc[0][7] = fmaf(w0, x3.y, acc[0][7]); acc[1][7] = fmaf(w1, x3.y, acc[1][7]);
    }
    #pragma unroll 2
    for (int i = 0; i < 32; ++i) {
        int d = sl + (i << 4);
        float w0 = wh0[d], w1 = wh1[d];
        const float2* a2 = (const float2*)(smem + (1024 + d) * 10);
        float2 x0 = a2[0], x1 = a2[1], x2 = a2[2], x3 = a2[3];
        acc[0][0] = fmaf(w0, x0.x, acc[0][0]); acc[1][0] = fmaf(w1, x0.x, acc[1][0]);
        acc[0][1] = fmaf(w0, x0.y, acc[0][1]); acc[1][1] = fmaf(w1, x0.y, acc[1][1]);
        acc[0][2] = fmaf(w0, x1.x, acc[0][2]); acc[1][2] = fmaf(w1, x1.x, acc[1][2]);
        acc[0][3] = fmaf(w0, x1.y, acc[0][3]); acc[1][3] = fmaf(w1, x1.y, acc[1][3]);
        acc[0][4] = fmaf(w0, x2.x, acc[0][4]); acc[1][4] = fmaf(w1, x2.x, acc[1][4]);
        acc[0][5] = fmaf(w0, x2.y, acc[0][5]); acc[1][5] = fmaf(w1, x2.y, acc[1][5]);
        acc[0][6] = fmaf(w0, x3.x, acc[0][6]); acc[1][6] = fmaf(w1, x3.x, acc[1][6]);
        acc[0][7] = fmaf(w0, x3.y, acc[0][7]); acc[1][7] = fmaf(w1, x3.y, acc[1][7]);
    }
    float* af = &acc[0][0];
    #pragma unroll
    for (int mk = 1; mk <= 8; mk <<= 1)
        #pragma unroll
        for (int k = 0; k < 16; ++k) af[k] += __shfl_xor(af[k], mk);
    __syncthreads();
    float* gred = smem;
    if (sl == 0) {
        #pragma unroll
        for (int q = 0; q < 8; ++q) {
            gred[(rt     ) * 8 + q] = acc[0][q];
            gred[(rt + 16) * 8 + q] = acc[1][q];
        }
    }
    __syncthreads();
    if (tid < 64) {
        int j2 = tid >> 3, bb = tid & 7;
        int jg = (jc << 3) + j2, bg = b0 + bb;
        float gv[4];
        #pragma unroll
        for (int g = 0; g < 4; ++g)
            gv[g] = gred[(g * 8 + j2) * 8 + bb] + E[idx_s[bb] * 2048 + g * 512 + jg];
        float ig = 1.f / (1.f + expf(-gv[0]));
        float fg = 1.f / (1.f + expf(-gv[1]));
        float gg = tanhf(gv[2]);
        float og = 1.f / (1.f + expf(-gv[3]));
        float cn = fg * c1[bg * 512 + jg] + ig * gg;
        c1[bg * 512 + jg] = cn;
        h1_out[bg * 512 + jg] = og * tanhf(cn);
    }
}

__global__ __launch_bounds__(256) void lstm1_fb(
    const float* __restrict__ h1n, const float* __restrict__ h2_in,
    float* __restrict__ c2, const float* __restrict__ Wih1,
    const float* __restrict__ Whh1, const float* __restrict__ bih1,
    const float* __restrict__ bhh1, float* __restrict__ h2_out)
{
    __shared__ alignas(16) float smem[1024 * 10];
    const int tid = threadIdx.x;
    const int jc = blockIdx.x;
    const int b0 = blockIdx.y << 3;
    {
        const int dc = tid & 31, bb = tid >> 5;
        const float* xrow = h1n  + (size_t)(b0 + bb) * 512;
        const float* hrow = h2_in + (size_t)(b0 + bb) * 512;
        #pragma unroll 4
        for (int i = 0; i < 16; ++i) { int d = dc + (i << 5); smem[d * 10 + bb] = xrow[d]; }
        #pragma unroll 4
        for (int i = 0; i < 16; ++i) { int d = dc + (i << 5); smem[(512 + d) * 10 + bb] = hrow[d]; }
    }
    __syncthreads();
    const int lane = tid & 63, wave = tid >> 6;
    const int sl = lane & 15;
    const int rt = (wave << 2) | (lane >> 4);
    const int g0r = ((rt      ) >> 3) * 512 + (jc << 3) + (rt & 7);
    const int g1r = ((rt + 16 ) >> 3) * 512 + (jc << 3) + (rt & 7);
    const float* wi0 = Wih1 + (size_t)g0r * 512;
    const float* wi1 = Wih1 + (size_t)g1r * 512;
    const float* wh0 = Whh1 + (size_t)g0r * 512;
    const float* wh1 = Whh1 + (size_t)g1r * 512;
    float acc[2][8];
    #pragma unroll
    for (int r = 0; r < 2; ++r)
        #pragma unroll
        for (int q = 0; q < 8; ++q) acc[r][q] = 0.f;
    #pragma unroll 2
    for (int i = 0; i < 32; ++i) {
        int d = sl + (i << 4);
        float w0 = wi0[d], w1 = wi1[d];
        const float2* a2 = (const float2*)(smem + d * 10);
        float2 x0 = a2[0], x1 = a2[1], x2 = a2[2], x3 = a2[3];
        acc[0][0] = fmaf(w0, x0.x, acc[0][0]); acc[1][0] = fmaf(w1, x0.x, acc[1][0]);
        acc[0][1] = fmaf(w0, x0.y, acc[0][1]); acc[1][1] = fmaf(w1, x0.y, acc[1][1]);
        acc[0][2] = fmaf(w0, x1.x, acc[0][2]); acc[1][2] = fmaf(w1, x1.x, acc[1][2]);
        acc[0][3] = fmaf(w0, x1.y, acc[0][3]); acc[1][3] = fmaf(w1, x1.y, acc[1][3]);
        acc[0][4] = fmaf(w0, x2.x, acc[0][4]); acc[1][4] = fmaf(w1, x2.x, acc[1][4]);
        acc[0][5] = fmaf(w0, x2.y, acc[0][5]); acc[1][5] = fmaf(w1, x2.y, acc[1][5]);
        acc[0][6] = fmaf(w0, x3.x, acc[0][6]); acc[1][6] = fmaf(w1, x3.x, acc[1][6]);
        acc[0][7] = fmaf(w0, x3.y, acc[0][7]); acc[1][7] = fmaf(w1, x3.y, acc[1][7]);
    }
    #pragma unroll 2
    for (int i = 0; i < 32; ++i) {
        int d = sl + (i << 4);
        float w0 = wh0[d], w1 = wh1[d];
        const float2* a2 = (const float2*)(smem + (512 + d) * 10);
        float2 x0 = a2[0], x1 = a2[1], x2 = a2[2], x3 = a2[3];
        acc[0][0] = fmaf(w0, x0.x, acc[0][0]); acc[1][0] = fmaf(w1, x0.x, acc[1][0]);
        acc[0][1] = fmaf(w0, x0.y, acc[0][1]); acc[1][1] = fmaf(w1, x0.y, acc[1][1]);
        acc[0][2] = fmaf(w0, x1.x, acc[0][2]); acc[1][2] = fmaf(w1, x1.x, acc[1][2]);
        acc[0][3] = fmaf(w0, x1.y, acc[0][3]); acc[1][3] = fmaf(w1, x1.y, acc[1][3]);
        acc[0][4] = fmaf(w0, x2.x, acc[0][4]); acc[1][4] = fmaf(w1, x2.x, acc[1][4]);
        acc[0][5] = fmaf(w0, x2.y, acc[0][5]); acc[1][5] = fmaf(w1, x2.y, acc[1][5]);
        acc[0][6] = fmaf(w0, x3.x, acc[0][6]); acc[1][6] = fmaf(w1, x3.x, acc[1][6]);
        acc[0][7] = fmaf(w0, x3.y, acc[0][7]); acc[1][7] = fmaf(w1, x3.y, acc[1][7]);
    }
    float* af = &acc[0][0];
    #pragma unroll
    for (int mk = 1; mk <= 8; mk <<= 1)
        #pragma unroll
        for (int k = 0; k < 16; ++k) af[k] += __shfl_xor(af[k], mk);
    __syncthreads();
    float* gred = smem;
    if (sl == 0) {
        #pragma unroll
        for (int q = 0; q < 8; ++q) {
            gred[(rt     ) * 8 + q] = acc[0][q];
            gred[(rt + 16) * 8 + q] = acc[1][q];
        }
    }
    __syncthreads();
    if (tid < 64) {
        int j2 = tid >> 3, bb = tid & 7;
        int jg = (jc << 3) + j2, bg = b0 + bb;
        float gv[4];
        #pragma unroll
        for (int g = 0; g < 4; ++g)
            gv[g] = gred[(g * 8 + j2) * 8 + bb] + bih1[g * 512 + jg] + bhh1[g * 512 + jg];
        float ig = 1.f / (1.f + expf(-gv[0]));
        float fg = 1.f / (1.f + expf(-gv[1]));
        float gg = tanhf(gv[2]);
        float og = 1.f / (1.f + expf(-gv[3]));
        float cn = fg * c2[bg * 512 + jg] + ig * gg;
        c2[bg * 512 + jg] = cn;
        h2_out[bg * 512 + jg] = og * tanhf(cn);
    }
}

__global__ __launch_bounds__(256) void tail_fb(
    const float* __restrict__ h2f, const float* __restrict__ Wl,
    const float* __restrict__ bl, const int* __restrict__ tgt,
    float* __restrict__ out)
{
    __shared__ float q_s[512];
    __shared__ float lg[3];
    const int b = blockIdx.x, tid = threadIdx.x;
    q_s[tid]       = h2f[b * 512 + tid];
    q_s[tid + 256] = h2f[b * 512 + 256 + tid];
    __syncthreads();
    if (tid < 192) {
        int v = tid >> 6, lane = tid & 63;
        float p = 0.f;
        #pragma unroll
        for (int j = 0; j < 8; ++j)
            p += q_s[lane * 8 + j] * Wl[v * 512 + lane * 8 + j];
        for (int off = 32; off; off >>= 1) p += __shfl_xor(p, off);
        if (lane == 0) lg[v] = p + bl[v];
    }
    __syncthreads();
    if (tid == 0) {
        float m = fmaxf(lg[0], fmaxf(lg[1], lg[2]));
        float e0 = expf(lg[0] - m), e1 = expf(lg[1] - m), e2 = expf(lg[2] - m);
        float ls = logf(e0 + e1 + e2);
        float* o = out + ((size_t)b * NT + (NT - 1)) * 3;
        o[0] = lg[0] - m - ls; o[1] = lg[1] - m - ls; o[2] = lg[2] - m - ls;
    }
    for (int i = tid; i < NT; i += 256)
        out[NB * NT * 3 + b * NT + i] = (float)tgt[b * NT + i];
}

// ---------------------------------------------------------------- launch
extern "C" void kernel_launch(void* const* d_in, const int* in_sizes, int n_in,
                              void* d_out, int out_size, void* d_ws, size_t ws_size,
                              hipStream_t stream)
{
    (void)in_sizes; (void)n_in; (void)out_size; (void)ws_size;
    const float* ctx  = (const float*)d_in[0];
    const int*   tgt  = (const int*)d_in[1];
    const float* h1_0 = (const float*)d_in[3];
    const float* c1_0 = (const float*)d_in[4];
    const float* h2_0 = (const float*)d_in[5];
    const float* c2_0 = (const float*)d_in[6];
    const float* emb  = (const float*)d_in[7];
    const float* Wih0 = (const float*)d_in[8];
    const float* Whh0 = (const float*)d_in[9];
    const float* bih0 = (const float*)d_in[10];
    const float* bhh0 = (const float*)d_in[11];
    const float* Wih1 = (const float*)d_in[12];
    const float* Whh1 = (const float*)d_in[13];
    const float* bih1 = (const float*)d_in[14];
    const float* bhh1 = (const float*)d_in[15];
    const float* Wl   = (const float*)d_in[16];
    const float* bl   = (const float*)d_in[17];
    float* out = (float*)d_out;

    float* f = (float*)d_ws;
    float* h1a   = f;              float* h1b = f + 32768;
    float* h2a   = f + 65536;      float* h2b = f + 98304;
    float* c1    = f + 131072;     float* c2  = f + 163840;
    float* E     = f + 196608;     // 3*2048
    float* pm    = f + 202752;     // 512
    float* pl    = f + 203264;     // 512
    float* pacc  = f + 203776;     // 512*1024 (coop uses 256*1024 of it)
    float* algn  = f + 728064;     // 64*1024
    int*   idx   = (int*)(f + 793600);   // 64
    int*   cnt   = idx + 64;             // 64

    init_kernel<<<128, 256, 0, stream>>>(h1_0, c1_0, h2_0, c2_0, tgt, h1a, c1, h2a, c2, idx, cnt);
    eproj_kernel<<<24, 256, 0, stream>>>(emb, Wih0, bih0, bhh0, E);

    DecP p;
    p.ctx = ctx; p.tgt = tgt;
    p.Wih0 = Wih0; p.Whh0 = Whh0; p.Wih1 = Wih1; p.Whh1 = Whh1;
    p.bih1 = bih1; p.bhh1 = bhh1; p.Wl = Wl; p.bl = bl;
    p.out = out;
    p.h1a = h1a; p.h1b = h1b; p.h2a = h2a; p.h2b = h2b;
    p.c1 = c1; p.c2 = c2; p.E = E;
    p.pm = pm; p.pl = pl; p.pacc = pacc; p.algn = algn;
    p.idx = idx; p.cnt = cnt;

    void* args[] = { &p };
    hipError_t err = hipLaunchCooperativeKernel((const void*)decoder_persist,
                                                dim3(256), dim3(512), args, 0, stream);
    if (err != hipSuccess) {
        (void)hipGetLastError();   // clear error state; run verified fallback path
        for (int t = 0; t < NT; ++t) {
            float* h1i = (t & 1) ? h1b : h1a;  float* h1o = (t & 1) ? h1a : h1b;
            float* h2i = (t & 1) ? h2b : h2a;  float* h2o = (t & 1) ? h2a : h2b;
            attn_fb<<<dim3(NCHF, NB), 256, 0, stream>>>(ctx, h2i, Wl, bl, pm, pl, pacc,
                                                        algn, cnt, idx, out, t);
            lstm0_fb<<<dim3(64, 8), 256, 0, stream>>>(algn, h1i, c1, E, idx, Wih0, Whh0, h1o);
            lstm1_fb<<<dim3(64, 8), 256, 0, stream>>>(h1o, h2i, c2, Wih1, Whh1, bih1, bhh1, h2o);
        }
        tail_fb<<<NB, 256, 0, stream>>>(h2a, Wl, bl, tgt, out);
    }
}

// Round 4
// 43325.647 us; speedup vs baseline: 1.6501x; 1.6501x over previous
//
#include <hip/hip_runtime.h>
#include <math.h>

// Persistent cooperative decoder: 500 steps of (attention -> lstm0 -> lstm1),
// 256 blocks x 512 threads. R4: cg::grid.sync() (~40us each, 60ms total per R3
// counters) replaced with custom two-level monotone barrier (~2-3us); attention
// inner loop unrolled to 4 ctx rows (16 outstanding loads/lane) for latency
// tolerance at 8 waves/CU.
// Fallback: if hipLaunchCooperativeKernel is rejected, run the round-1
// verified per-step kernel path (slower but correct).

#define NB 64
#define NS 500
#define NT 500

struct DecP {
    const float* ctx; const int* tgt;
    const float* Wih0; const float* Whh0;
    const float* Wih1; const float* Whh1;
    const float* bih1; const float* bhh1;
    const float* Wl;   const float* bl;
    float* out;
    float* h1a; float* h1b; float* h2a; float* h2b;
    float* c1;  float* c2;  float* E;
    float* pm;  float* pl;  float* pacc; float* algn;
    int* idx;   int* cnt;   int* bar;
};

// Two-level grid barrier: leaves bar[(blk&7)*32], root bar[256], flag bar[288].
// Monotone counters (init zeroes them each launch); gen is the 1-based barrier
// index. Release: __syncthreads drains vmcnt, tid0 __threadfence (wbl2).
// Acquire: tid0 __threadfence (inv L1/L2) after flag, then __syncthreads.
__device__ __forceinline__ void fast_bar(int* bar, int gen)
{
    __syncthreads();
    if (threadIdx.x == 0) {
        __threadfence();
        int li = (blockIdx.x & 7) * 32;
        int a = __hip_atomic_fetch_add(&bar[li], 1, __ATOMIC_RELAXED, __HIP_MEMORY_SCOPE_AGENT);
        if (a == gen * 32 - 1) {
            int r = __hip_atomic_fetch_add(&bar[256], 1, __ATOMIC_RELAXED, __HIP_MEMORY_SCOPE_AGENT);
            if (r == gen * 8 - 1)
                __hip_atomic_store(&bar[288], gen, __ATOMIC_RELAXED, __HIP_MEMORY_SCOPE_AGENT);
        }
        while (__hip_atomic_load(&bar[288], __ATOMIC_RELAXED, __HIP_MEMORY_SCOPE_AGENT) < gen)
            __builtin_amdgcn_s_sleep(2);
        __threadfence();
    }
    __syncthreads();
}

// ---------------------------------------------------------------- init
__global__ __launch_bounds__(256) void init_kernel(
    const float* __restrict__ h1_0, const float* __restrict__ c1_0,
    const float* __restrict__ h2_0, const float* __restrict__ c2_0,
    const int* __restrict__ tgt,
    float* __restrict__ h1a, float* __restrict__ c1,
    float* __restrict__ h2a, float* __restrict__ c2,
    int* __restrict__ idx, int* __restrict__ cnt, int* __restrict__ bar)
{
    int gid = blockIdx.x * 256 + threadIdx.x;   // grid 128 -> 32768
    h1a[gid] = h1_0[gid];
    c1[gid]  = c1_0[gid];
    h2a[gid] = h2_0[gid];
    c2[gid]  = c2_0[gid];
    if (gid < NB) { idx[gid] = tgt[gid * NT]; cnt[gid] = 0; }
    if (gid < 512) bar[gid] = 0;
}

// ------------------------------------------------- E = emb @ W_ih0[:, :512].T + b_ih0 + b_hh0
__global__ __launch_bounds__(256) void eproj_kernel(
    const float* __restrict__ emb, const float* __restrict__ Wih0,
    const float* __restrict__ bih0, const float* __restrict__ bhh0,
    float* __restrict__ E)
{
    int gid = blockIdx.x * 256 + threadIdx.x;   // grid 24 -> 6144 = 3*2048
    int v = gid >> 11, g = gid & 2047;
    const float4* wr = (const float4*)(Wih0 + (size_t)g * 1536);
    const float4* er = (const float4*)(emb + v * 512);
    float s = bih0[g] + bhh0[g];
    #pragma unroll 4
    for (int i = 0; i < 128; ++i) {
        float4 w = wr[i], e = er[i];
        s += w.x*e.x + w.y*e.y + w.z*e.z + w.w*e.w;
    }
    E[v * 2048 + g] = s;
}

// ---------------------------------------------------------------- persistent decoder
__global__ __launch_bounds__(512, 2) void decoder_persist(DecP P)
{
    __shared__ float smem[14592];   // 58368 B
    __shared__ float wm[8], wls[8];
    __shared__ float lg[3];
    __shared__ int   is_last;
    __shared__ int   idx_s[8];

    const int tid  = threadIdx.x;
    const int blk  = blockIdx.x;
    const int lane = tid & 63, wave = tid >> 6;

    const int b_at = blk & 63, ch = blk >> 6;   // attention: 64 b x 4 chunks
    const int jc2  = blk & 31, bg = blk >> 5;   // gemm: 32 j-chunks(16j) x 8 b-groups

    float* h1i = P.h1a; float* h1o = P.h1b;
    float* h2i = P.h2a; float* h2o = P.h2b;
    int gen = 0;

    #pragma unroll 1
    for (int t = 0; t < NT; ++t) {
        // ================= Phase A: logits(t-1) + attention =================
        {
            float* q_s  = smem;          // 512
            float* wacc = smem + 512;    // 8*1024
            q_s[tid] = h2i[b_at * 512 + tid];
            __syncthreads();

            if (ch == 0 && t > 0) {      // block-uniform branch
                if (tid < 192) {
                    int v = tid >> 6;
                    float p = 0.f;
                    #pragma unroll
                    for (int j = 0; j < 8; ++j)
                        p += q_s[lane * 8 + j] * P.Wl[v * 512 + lane * 8 + j];
                    #pragma unroll
                    for (int off = 32; off; off >>= 1) p += __shfl_xor(p, off);
                    if (lane == 0) lg[v] = p + P.bl[v];
                }
                __syncthreads();
                if (tid == 0) {
                    float m = fmaxf(lg[0], fmaxf(lg[1], lg[2]));
                    float e0 = expf(lg[0] - m), e1 = expf(lg[1] - m), e2 = expf(lg[2] - m);
                    float ls = logf(e0 + e1 + e2);
                    float* o = P.out + ((size_t)b_at * NT + (t - 1)) * 3;
                    o[0] = lg[0] - m - ls; o[1] = lg[1] - m - ls; o[2] = lg[2] - m - ls;
                    int am = 0;
                    if (lg[1] > lg[am]) am = 1;
                    if (lg[2] > lg[am]) am = 2;
                    P.idx[b_at] = am;
                }
            }

            const int s0 = ch * 125;
            const int se = s0 + 125;               // 4*125 = 500 exact
            int sA = s0 + wave * 16;
            int sB = sA + 16; if (sB > se) sB = se;
            float4 q0 = ((const float4*)q_s)[lane];
            float4 q1 = ((const float4*)q_s)[64 + lane];
            float m = -INFINITY, l = 0.f;
            float4 a0 = {0,0,0,0}, a1 = {0,0,0,0}, a2 = {0,0,0,0}, a3 = {0,0,0,0};

            for (int s = sA; s < sB; s += 4) {
                float4 rr[4][4];
                #pragma unroll
                for (int k = 0; k < 4; ++k) {
                    int ridx = (s + k < sB) ? s + k : s;
                    const float4* rp = (const float4*)(P.ctx + ((size_t)b_at * NS + ridx) * 1024);
                    rr[k][0] = rp[lane];       rr[k][1] = rp[64 + lane];
                    rr[k][2] = rp[128 + lane]; rr[k][3] = rp[192 + lane];
                }
                float p[4];
                #pragma unroll
                for (int k = 0; k < 4; ++k) {
                    float4 c0 = rr[k][0], c1 = rr[k][1], c2 = rr[k][2], c3 = rr[k][3];
                    // q = cat(h2,h2): d>=512 wraps to q0/q1
                    p[k] = c0.x*q0.x + c0.y*q0.y + c0.z*q0.z + c0.w*q0.w
                         + c1.x*q1.x + c1.y*q1.y + c1.z*q1.z + c1.w*q1.w
                         + c2.x*q0.x + c2.y*q0.y + c2.z*q0.z + c2.w*q0.w
                         + c3.x*q1.x + c3.y*q1.y + c3.z*q1.z + c3.w*q1.w;
                }
                #pragma unroll
                for (int off = 32; off; off >>= 1) {
                    p[0] += __shfl_xor(p[0], off);
                    p[1] += __shfl_xor(p[1], off);
                    p[2] += __shfl_xor(p[2], off);
                    p[3] += __shfl_xor(p[3], off);
                }
                #pragma unroll
                for (int k = 1; k < 4; ++k)
                    if (s + k >= sB) p[k] = -INFINITY;
                float mn = fmaxf(m, fmaxf(fmaxf(p[0], p[1]), fmaxf(p[2], p[3])));
                float al = expf(m - mn);        // first iter: exp(-inf)=0
                float w[4];
                #pragma unroll
                for (int k = 0; k < 4; ++k) w[k] = expf(p[k] - mn);   // invalid -> 0
                l = l * al + w[0] + w[1] + w[2] + w[3];
                #pragma unroll
                for (int c = 0; c < 4; ++c) {
                    float4* ac = (c == 0) ? &a0 : (c == 1) ? &a1 : (c == 2) ? &a2 : &a3;
                    ac->x = fmaf(w[3], rr[3][c].x, fmaf(w[2], rr[2][c].x, fmaf(w[1], rr[1][c].x, fmaf(w[0], rr[0][c].x, ac->x * al))));
                    ac->y = fmaf(w[3], rr[3][c].y, fmaf(w[2], rr[2][c].y, fmaf(w[1], rr[1][c].y, fmaf(w[0], rr[0][c].y, ac->y * al))));
                    ac->z = fmaf(w[3], rr[3][c].z, fmaf(w[2], rr[2][c].z, fmaf(w[1], rr[1][c].z, fmaf(w[0], rr[0][c].z, ac->z * al))));
                    ac->w = fmaf(w[3], rr[3][c].w, fmaf(w[2], rr[2][c].w, fmaf(w[1], rr[1][c].w, fmaf(w[0], rr[0][c].w, ac->w * al))));
                }
                m = mn;
            }
            ((float4*)wacc)[wave*256 + lane]       = a0;
            ((float4*)wacc)[wave*256 + 64 + lane]  = a1;
            ((float4*)wacc)[wave*256 + 128 + lane] = a2;
            ((float4*)wacc)[wave*256 + 192 + lane] = a3;
            if (lane == 0) { wm[wave] = m; wls[wave] = l; }
            __syncthreads();
            {   // combine 8 wave partials -> chunk partial (each thread 2 d's)
                float M = wm[0];
                #pragma unroll
                for (int w = 1; w < 8; ++w) M = fmaxf(M, wm[w]);
                float e[8]; float L = 0.f;
                #pragma unroll
                for (int w = 0; w < 8; ++w) { e[w] = expf(wm[w] - M); L += e[w] * wls[w]; }
                int d2 = tid * 2;
                float rx = 0.f, ry = 0.f;
                #pragma unroll
                for (int w = 0; w < 8; ++w) {
                    float2 x = *(float2*)&wacc[w*1024 + d2];
                    rx = fmaf(e[w], x.x, rx); ry = fmaf(e[w], x.y, ry);
                }
                *(float2*)&P.pacc[((size_t)(b_at*4 + ch))*1024 + d2] = make_float2(rx, ry);
                if (tid == 0) { P.pm[b_at*4 + ch] = M; P.pl[b_at*4 + ch] = L; }
            }
            __syncthreads();
            if (tid == 0) {
                __threadfence();
                int old = __hip_atomic_fetch_add(P.cnt + b_at, 1, __ATOMIC_ACQ_REL,
                                                 __HIP_MEMORY_SCOPE_AGENT);
                is_last = (old == 4*t + 3) ? 1 : 0;     // monotone counter
            }
            __syncthreads();
            if (is_last) {      // combine 4 chunks -> align[b]
                float M = -INFINITY;
                #pragma unroll
                for (int k = 0; k < 4; ++k) M = fmaxf(M, P.pm[b_at*4 + k]);
                float e[4]; float L = 0.f;
                #pragma unroll
                for (int k = 0; k < 4; ++k) { e[k] = expf(P.pm[b_at*4 + k] - M); L += e[k] * P.pl[b_at*4 + k]; }
                float invL = 1.f / L;
                int d2 = tid * 2;
                float rx = 0.f, ry = 0.f;
                #pragma unroll
                for (int k = 0; k < 4; ++k) {
                    float2 x = *(float2*)&P.pacc[((size_t)(b_at*4 + k))*1024 + d2];
                    rx = fmaf(e[k], x.x, rx); ry = fmaf(e[k], x.y, ry);
                }
                *(float2*)&P.algn[b_at*1024 + d2] = make_float2(rx*invL, ry*invL);
            }
        }
        fast_bar(P.bar, ++gen);
        // ================= Phase B: lstm0 -> h1 =================
        {
            float* x0    = smem;           // 8 b x 1536 k  [b][k]
            float* gred2 = smem + 12288;   // 8 rg x 8 kgrp x 32
            float* gred  = smem + 14336;   // 256
            if (tid < 8) idx_s[tid] = P.idx[bg*8 + tid];
            #pragma unroll
            for (int j = 0; j < 6; ++j) {
                int i4 = tid + j*512;               // 0..3071 float4s
                int bb = i4 / 384, r = i4 - bb*384;
                int b = bg*8 + bb;
                float4 v = (r < 256) ? ((const float4*)(P.algn + b*1024))[r]
                                     : ((const float4*)(h1i + b*512))[r - 256];
                ((float4*)x0)[i4] = v;
            }
            __syncthreads();
            const int rg = wave;
            const int g = rg >> 1, qq = (rg & 1) * 4;
            #pragma unroll 1
            for (int p = 0; p < 2; ++p) {
                const int jc = jc2*2 + p;
                const int row0 = g*512 + jc*8 + qq;     // rows row0..row0+3
                float af[32];
                #pragma unroll
                for (int q = 0; q < 32; ++q) af[q] = 0.f;
                #pragma unroll
                for (int i = 0; i < 6; ++i) {
                    int k = i*256 + lane*4;
                    float4 w0, w1, w2, w3;
                    if (i < 4) {
                        const float* wb = P.Wih0 + (size_t)row0*1536 + 512 + k;
                        w0 = *(const float4*)(wb);
                        w1 = *(const float4*)(wb + 1536);
                        w2 = *(const float4*)(wb + 3072);
                        w3 = *(const float4*)(wb + 4608);
                    } else {
                        const float* wb = P.Whh0 + (size_t)row0*512 + (k - 1024);
                        w0 = *(const float4*)(wb);
                        w1 = *(const float4*)(wb + 512);
                        w2 = *(const float4*)(wb + 1024);
                        w3 = *(const float4*)(wb + 1536);
                    }
                    #pragma unroll
                    for (int bb = 0; bb < 8; ++bb) {
                        float4 x = *(const float4*)&x0[bb*1536 + k];
                        af[0*8+bb] = fmaf(w0.w, x.w, fmaf(w0.z, x.z, fmaf(w0.y, x.y, fmaf(w0.x, x.x, af[0*8+bb]))));
                        af[1*8+bb] = fmaf(w1.w, x.w, fmaf(w1.z, x.z, fmaf(w1.y, x.y, fmaf(w1.x, x.x, af[1*8+bb]))));
                        af[2*8+bb] = fmaf(w2.w, x.w, fmaf(w2.z, x.z, fmaf(w2.y, x.y, fmaf(w2.x, x.x, af[2*8+bb]))));
                        af[3*8+bb] = fmaf(w3.w, x.w, fmaf(w3.z, x.z, fmaf(w3.y, x.y, fmaf(w3.x, x.x, af[3*8+bb]))));
                    }
                }
                #pragma unroll
                for (int mm = 1; mm <= 4; mm <<= 1) {
                    #pragma unroll
                    for (int q = 0; q < 32; ++q) af[q] += __shfl_xor(af[q], mm);
                }
                if ((lane & 7) == 0) {
                    const int kg = lane >> 3;
                    float* gdst = gred2 + rg*256 + kg*32;
                    #pragma unroll
                    for (int q = 0; q < 8; ++q)
                        *(float4*)(gdst + q*4) = make_float4(af[q*4], af[q*4+1], af[q*4+2], af[q*4+3]);
                }
                __syncthreads();
                if (tid < 256) {
                    int rb = tid >> 3, bb = tid & 7;
                    int rg2 = rb >> 2, rr2 = rb & 3;
                    float s = 0.f;
                    #pragma unroll
                    for (int kg = 0; kg < 8; ++kg) s += gred2[rg2*256 + kg*32 + rr2*8 + bb];
                    gred[tid] = s;   // gred[(g*8+jj)*8+bb]
                }
                __syncthreads();
                if (tid < 64) {
                    int jj = tid >> 3, bb = tid & 7;
                    int j = jc*8 + jj, b = bg*8 + bb;
                    float gv[4];
                    #pragma unroll
                    for (int gg = 0; gg < 4; ++gg)
                        gv[gg] = gred[(gg*8 + jj)*8 + bb] + P.E[idx_s[bb]*2048 + gg*512 + j];
                    float ig = 1.f / (1.f + expf(-gv[0]));
                    float fg = 1.f / (1.f + expf(-gv[1]));
                    float g2 = tanhf(gv[2]);
                    float og = 1.f / (1.f + expf(-gv[3]));
                    float cn = fg * P.c1[b*512 + j] + ig * g2;
                    P.c1[b*512 + j] = cn;
                    h1o[b*512 + j] = og * tanhf(cn);
                }
            }
        }
        fast_bar(P.bar, ++gen);
        // ================= Phase C: lstm1 -> h2 =================
        {
            float* x1    = smem;           // 8 b x 1024 k  [b][k]
            float* gred2 = smem + 12288;
            float* gred  = smem + 14336;
            #pragma unroll
            for (int j = 0; j < 4; ++j) {
                int i4 = tid + j*512;               // 0..2047 float4s
                int bb = i4 >> 8, r = i4 & 255;
                int b = bg*8 + bb;
                float4 v = (r < 128) ? ((const float4*)(h1o + b*512))[r]
                                     : ((const float4*)(h2i + b*512))[r - 128];
                ((float4*)x1)[i4] = v;
            }
            __syncthreads();
            const int rg = wave;
            const int g = rg >> 1, qq = (rg & 1) * 4;
            #pragma unroll 1
            for (int p = 0; p < 2; ++p) {
                const int jc = jc2*2 + p;
                const int row0 = g*512 + jc*8 + qq;
                float af[32];
                #pragma unroll
                for (int q = 0; q < 32; ++q) af[q] = 0.f;
                #pragma unroll
                for (int i = 0; i < 4; ++i) {
                    int k = i*256 + lane*4;
                    float4 w0, w1, w2, w3;
                    if (i < 2) {
                        const float* wb = P.Wih1 + (size_t)row0*512 + k;
                        w0 = *(const float4*)(wb);
                        w1 = *(const float4*)(wb + 512);
                        w2 = *(const float4*)(wb + 1024);
                        w3 = *(const float4*)(wb + 1536);
                    } else {
                        const float* wb = P.Whh1 + (size_t)row0*512 + (k - 512);
                        w0 = *(const float4*)(wb);
                        w1 = *(const float4*)(wb + 512);
                        w2 = *(const float4*)(wb + 1024);
                        w3 = *(const float4*)(wb + 1536);
                    }
                    #pragma unroll
                    for (int bb = 0; bb < 8; ++bb) {
                        float4 x = *(const float4*)&x1[bb*1024 + k];
                        af[0*8+bb] = fmaf(w0.w, x.w, fmaf(w0.z, x.z, fmaf(w0.y, x.y, fmaf(w0.x, x.x, af[0*8+bb]))));
                        af[1*8+bb] = fmaf(w1.w, x.w, fmaf(w1.z, x.z, fmaf(w1.y, x.y, fmaf(w1.x, x.x, af[1*8+bb]))));
                        af[2*8+bb] = fmaf(w2.w, x.w, fmaf(w2.z, x.z, fmaf(w2.y, x.y, fmaf(w2.x, x.x, af[2*8+bb]))));
                        af[3*8+bb] = fmaf(w3.w, x.w, fmaf(w3.z, x.z, fmaf(w3.y, x.y, fmaf(w3.x, x.x, af[3*8+bb]))));
                    }
                }
                #pragma unroll
                for (int mm = 1; mm <= 4; mm <<= 1) {
                    #pragma unroll
                    for (int q = 0; q < 32; ++q) af[q] += __shfl_xor(af[q], mm);
                }
                if ((lane & 7) == 0) {
                    const int kg = lane >> 3;
                    float* gdst = gred2 + rg*256 + kg*32;
                    #pragma unroll
                    for (int q = 0; q < 8; ++q)
                        *(float4*)(gdst + q*4) = make_float4(af[q*4], af[q*4+1], af[q*4+2], af[q*4+3]);
                }
                __syncthreads();
                if (tid < 256) {
                    int rb = tid >> 3, bb = tid & 7;
                    int rg2 = rb >> 2, rr2 = rb & 3;
                    float s = 0.f;
                    #pragma unroll
                    for (int kg = 0; kg < 8; ++kg) s += gred2[rg2*256 + kg*32 + rr2*8 + bb];
                    gred[tid] = s;
                }
                __syncthreads();
                if (tid < 64) {
                    int jj = tid >> 3, bb = tid & 7;
                    int j = jc*8 + jj, b = bg*8 + bb;
                    float gv[4];
                    #pragma unroll
                    for (int gg = 0; gg < 4; ++gg)
                        gv[gg] = gred[(gg*8 + jj)*8 + bb] + P.bih1[gg*512 + j] + P.bhh1[gg*512 + j];
                    float ig = 1.f / (1.f + expf(-gv[0]));
                    float fg = 1.f / (1.f + expf(-gv[1]));
                    float g2 = tanhf(gv[2]);
                    float og = 1.f / (1.f + expf(-gv[3]));
                    float cn = fg * P.c2[b*512 + j] + ig * g2;
                    P.c2[b*512 + j] = cn;
                    h2o[b*512 + j] = og * tanhf(cn);
                }
            }
        }
        fast_bar(P.bar, ++gen);
        // swap state buffers
        float* tsw;
        tsw = h1i; h1i = h1o; h1o = tsw;
        tsw = h2i; h2i = h2o; h2o = tsw;
    }
    // ================= tail: logits(499) + target copy =================
    if (blk < NB) {
        const int b = blk;
        float* q_s = smem;
        q_s[tid] = h2i[b*512 + tid];
        __syncthreads();
        if (tid < 192) {
            int v = tid >> 6;
            float p = 0.f;
            #pragma unroll
            for (int j = 0; j < 8; ++j)
                p += q_s[lane*8 + j] * P.Wl[v*512 + lane*8 + j];
            #pragma unroll
            for (int off = 32; off; off >>= 1) p += __shfl_xor(p, off);
            if (lane == 0) lg[v] = p + P.bl[v];
        }
        __syncthreads();
        if (tid == 0) {
            float m = fmaxf(lg[0], fmaxf(lg[1], lg[2]));
            float e0 = expf(lg[0]-m), e1 = expf(lg[1]-m), e2 = expf(lg[2]-m);
            float ls = logf(e0 + e1 + e2);
            float* o = P.out + ((size_t)b*NT + (NT-1))*3;
            o[0] = lg[0]-m-ls; o[1] = lg[1]-m-ls; o[2] = lg[2]-m-ls;
        }
        for (int i = tid; i < NT; i += 512)
            P.out[NB*NT*3 + b*NT + i] = (float)P.tgt[b*NT + i];
    }
}

// ================================================================ fallback path
// Round-1 verified per-step kernels (used only if cooperative launch is rejected).
#define NCHF 8
#define CHSF 63

__global__ __launch_bounds__(256) void attn_fb(
    const float* __restrict__ ctx, const float* __restrict__ h2_in,
    const float* __restrict__ Wl, const float* __restrict__ bl,
    float* __restrict__ pm, float* __restrict__ pl, float* __restrict__ pacc,
    float* __restrict__ align_g, int* __restrict__ cnt, int* __restrict__ idx,
    float* __restrict__ out, int t)
{
    __shared__ alignas(16) float q_s[512];
    __shared__ alignas(16) float wacc[4 * 1024];
    __shared__ float wm[4], wl_s[4];
    __shared__ float lg[3];
    __shared__ int is_last;
    const int tid = threadIdx.x;
    const int ch = blockIdx.x, b = blockIdx.y;

    q_s[tid]       = h2_in[b * 512 + tid];
    q_s[tid + 256] = h2_in[b * 512 + 256 + tid];
    __syncthreads();

    if (ch == 0 && t > 0) {
        if (tid < 192) {
            int v = tid >> 6, lane = tid & 63;
            float p = 0.f;
            #pragma unroll
            for (int j = 0; j < 8; ++j)
                p += q_s[lane * 8 + j] * Wl[v * 512 + lane * 8 + j];
            for (int off = 32; off; off >>= 1) p += __shfl_xor(p, off);
            if (lane == 0) lg[v] = p + bl[v];
        }
        __syncthreads();
        if (tid == 0) {
            float m = fmaxf(lg[0], fmaxf(lg[1], lg[2]));
            float e0 = expf(lg[0] - m), e1 = expf(lg[1] - m), e2 = expf(lg[2] - m);
            float ls = logf(e0 + e1 + e2);
            float* o = out + ((size_t)b * NT + (t - 1)) * 3;
            o[0] = lg[0] - m - ls; o[1] = lg[1] - m - ls; o[2] = lg[2] - m - ls;
            int am = 0;
            if (lg[1] > lg[am]) am = 1;
            if (lg[2] > lg[am]) am = 2;
            idx[b] = am;
        }
    }

    const int lane = tid & 63, wave = tid >> 6;
    const int s0 = ch * CHSF;
    const int s1 = (s0 + CHSF < NS) ? s0 + CHSF : NS;
    float4 q0 = ((const float4*)q_s)[lane];
    float4 q1 = ((const float4*)q_s)[64 + lane];
    float m = -INFINITY, l = 0.f;
    float4 a0 = {0,0,0,0}, a1 = {0,0,0,0}, a2 = {0,0,0,0}, a3 = {0,0,0,0};

    for (int s = s0 + wave; s < s1; s += 4) {
        const float4* crow = (const float4*)(ctx + ((size_t)b * NS + s) * 1024);
        float4 v0 = crow[lane], v1 = crow[64 + lane], v2 = crow[128 + lane], v3 = crow[192 + lane];
        float p = v0.x*q0.x + v0.y*q0.y + v0.z*q0.z + v0.w*q0.w
                + v1.x*q1.x + v1.y*q1.y + v1.z*q1.z + v1.w*q1.w
                + v2.x*q0.x + v2.y*q0.y + v2.z*q0.z + v2.w*q0.w
                + v3.x*q1.x + v3.y*q1.y + v3.z*q1.z + v3.w*q1.w;
        for (int off = 32; off; off >>= 1) p += __shfl_xor(p, off);
        float mn = fmaxf(m, p);
        float al = expf(m - mn);
        float w  = expf(p - mn);
        l = l * al + w;
        a0.x = a0.x*al + w*v0.x; a0.y = a0.y*al + w*v0.y; a0.z = a0.z*al + w*v0.z; a0.w = a0.w*al + w*v0.w;
        a1.x = a1.x*al + w*v1.x; a1.y = a1.y*al + w*v1.y; a1.z = a1.z*al + w*v1.z; a1.w = a1.w*al + w*v1.w;
        a2.x = a2.x*al + w*v2.x; a2.y = a2.y*al + w*v2.y; a2.z = a2.z*al + w*v2.z; a2.w = a2.w*al + w*v2.w;
        a3.x = a3.x*al + w*v3.x; a3.y = a3.y*al + w*v3.y; a3.z = a3.z*al + w*v3.z; a3.w = a3.w*al + w*v3.w;
        m = mn;
    }
    ((float4*)wacc)[wave * 256 + lane]       = a0;
    ((float4*)wacc)[wave * 256 + 64 + lane]  = a1;
    ((float4*)wacc)[wave * 256 + 128 + lane] = a2;
    ((float4*)wacc)[wave * 256 + 192 + lane] = a3;
    if (lane == 0) { wm[wave] = m; wl_s[wave] = l; }
    __syncthreads();
    {
        float M = fmaxf(fmaxf(wm[0], wm[1]), fmaxf(wm[2], wm[3]));
        float e0 = expf(wm[0]-M), e1 = expf(wm[1]-M), e2 = expf(wm[2]-M), e3 = expf(wm[3]-M);
        float L = e0*wl_s[0] + e1*wl_s[1] + e2*wl_s[2] + e3*wl_s[3];
        const float4* w4 = (const float4*)wacc;
        float4 x0 = w4[tid], x1 = w4[256 + tid], x2 = w4[512 + tid], x3 = w4[768 + tid];
        float4 r;
        r.x = e0*x0.x + e1*x1.x + e2*x2.x + e3*x3.x;
        r.y = e0*x0.y + e1*x1.y + e2*x2.y + e3*x3.y;
        r.z = e0*x0.z + e1*x1.z + e2*x2.z + e3*x3.z;
        r.w = e0*x0.w + e1*x1.w + e2*x2.w + e3*x3.w;
        ((float4*)pacc)[(b * NCHF + ch) * 256 + tid] = r;
        if (tid == 0) { pm[b * NCHF + ch] = M; pl[b * NCHF + ch] = L; }
    }
    __syncthreads();
    if (tid == 0) {
        __threadfence();
        int old = __hip_atomic_fetch_add(cnt + b, 1, __ATOMIC_ACQ_REL, __HIP_MEMORY_SCOPE_AGENT);
        is_last = (old == NCHF * t + (NCHF - 1)) ? 1 : 0;
    }
    __syncthreads();
    if (is_last) {
        float M = -INFINITY;
        #pragma unroll
        for (int k = 0; k < NCHF; ++k) M = fmaxf(M, pm[b * NCHF + k]);
        float e[NCHF]; float L = 0.f;
        #pragma unroll
        for (int k = 0; k < NCHF; ++k) { e[k] = expf(pm[b * NCHF + k] - M); L += e[k] * pl[b * NCHF + k]; }
        float invL = 1.f / L;
        const float4* p4 = (const float4*)pacc;
        float4 r = {0,0,0,0};
        #pragma unroll
        for (int k = 0; k < NCHF; ++k) {
            float4 x = p4[(b * NCHF + k) * 256 + tid];
            r.x += e[k]*x.x; r.y += e[k]*x.y; r.z += e[k]*x.z; r.w += e[k]*x.w;
        }
        r.x *= invL; r.y *= invL; r.z *= invL; r.w *= invL;
        ((float4*)align_g)[b * 256 + tid] = r;
    }
}

__global__ __launch_bounds__(256) void lstm0_fb(
    const float* __restrict__ align_g, const float* __restrict__ h1_in,
    float* __restrict__ c1, const float* __restrict__ E,
    const int* __restrict__ idx, const float* __restrict__ Wih0,
    const float* __restrict__ Whh0, float* __restrict__ h1_out)
{
    __shared__ alignas(16) float smem[1536 * 10];
    __shared__ int idx_s[8];
    const int tid = threadIdx.x;
    const int jc = blockIdx.x;
    const int b0 = blockIdx.y << 3;
    {
        const int dc = tid & 31, bb = tid >> 5;
        const float* arow = align_g + (size_t)(b0 + bb) * 1024;
        const float* hrow = h1_in + (size_t)(b0 + bb) * 512;
        #pragma unroll 4
        for (int i = 0; i < 32; ++i) { int d = dc + (i << 5); smem[d * 10 + bb] = arow[d]; }
        #pragma unroll 4
        for (int i = 0; i < 16; ++i) { int d = dc + (i << 5); smem[(1024 + d) * 10 + bb] = hrow[d]; }
        if (tid < 8) idx_s[tid] = idx[b0 + tid];
    }
    __syncthreads();
    const int lane = tid & 63, wave = tid >> 6;
    const int sl = lane & 15;
    const int rt = (wave << 2) | (lane >> 4);
    const int g0r = ((rt      ) >> 3) * 512 + (jc << 3) + (rt & 7);
    const int g1r = ((rt + 16 ) >> 3) * 512 + (jc << 3) + (rt & 7);
    const float* wa0 = Wih0 + (size_t)g0r * 1536 + 512;
    const float* wa1 = Wih0 + (size_t)g1r * 1536 + 512;
    const float* wh0 = Whh0 + (size_t)g0r * 512;
    const float* wh1 = Whh0 + (size_t)g1r * 512;
    float acc[2][8];
    #pragma unroll
    for (int r = 0; r < 2; ++r)
        #pragma unroll
        for (int q = 0; q < 8; ++q) acc[r][q] = 0.f;
    #pragma unroll 2
    for (int i = 0; i < 64; ++i) {
        int d = sl + (i << 4);
        float w0 = wa0[d], w1 = wa1[d];
        const float2* a2 = (const float2*)(smem + d * 10);
        float2 x0 = a2[0], x1 = a2[1], x2 = a2[2], x3 = a2[3];
        acc[0][0] = fmaf(w0, x0.x, acc[0][0]); acc[1][0] = fmaf(w1, x0.x, acc[1][0]);
        acc[0][1] = fmaf(w0, x0.y, acc[0][1]); acc[1][1] = fmaf(w1, x0.y, acc[1][1]);
        acc[0][2] = fmaf(w0, x1.x, acc[0][2]); acc[1][2] = fmaf(w1, x1.x, acc[1][2]);
        acc[0][3] = fmaf(w0, x1.y, acc[0][3]); acc[1][3] = fmaf(w1, x1.y, acc[1][3]);
        acc[0][4] = fmaf(w0, x2.x, acc[0][4]); acc[1][4] = fmaf(w1, x2.x, acc[1][4]);
        acc[0][5] = fmaf(w0, x2.y, acc[0][5]); acc[1][5] = fmaf(w1, x2.y, acc[1][5]);
        acc[0][6] = fmaf(w0, x3.x, acc[0][6]); acc[1][6] = fmaf(w1, x3.x, acc[1][6]);
        acc[0][7] = fmaf(w0, x3.y, acc[0][7]); acc[1][7] = fmaf(w1, x3.y, acc[1][7]);
    }
    #pragma unroll 2
    for (int i = 0; i < 32; ++i) {
        int d = sl + (i << 4);
        float w0 = wh0[d], w1 = wh1[d];
        const float2* a2 = (const float2*)(smem + (1024 + d) * 10);
        float2 x0 = a2[0], x1 = a2[1], x2 = a2[2], x3 = a2[3];
        acc[0][0] = fmaf(w0, x0.x, acc[0][0]); acc[1][0] = fmaf(w1, x0.x, acc[1][0]);
        acc[0][1] = fmaf(w0, x0.y, acc[0][1]); acc[1][1] = fmaf(w1, x0.y, acc[1][1]);
        acc[0][2] = fmaf(w0, x1.x, acc[0][2]); acc[1][2] = fmaf(w1, x1.x, acc[1][2]);
        acc[0][3] = fmaf(w0, x1.y, acc[0][3]); acc[1][3] = fmaf(w1, x1.y, acc[1][3]);
        acc[0][4] = fmaf(w0, x2.x, acc[0][4]); acc[1][4] = fmaf(w1, x2.x, acc[1][4]);
        acc[0][5] = fmaf(w0, x2.y, acc[0][5]); acc[1][5] = fmaf(w1, x2.y, acc[1][5]);
        acc[0][6] = fmaf(w0, x3.x, acc[0][6]); acc[1][6] = fmaf(w1, x3.x, acc[1][6]);
        acc[0][7] = fmaf(w0, x3.y, acc[0][7]); acc[1][7] = fmaf(w1, x3.y, acc[1][7]);
    }
    float* af = &acc[0][0];
    #pragma unroll
    for (int mk = 1; mk <= 8; mk <<= 1)
        #pragma unroll
        for (int k = 0; k < 16; ++k) af[k] += __shfl_xor(af[k], mk);
    __syncthreads();
    float* gred = smem;
    if (sl == 0) {
        #pragma unroll
        for (int q = 0; q < 8; ++q) {
            gred[(rt     ) * 8 + q] = acc[0][q];
            gred[(rt + 16) * 8 + q] = acc[1][q];
        }
    }
    __syncthreads();
    if (tid < 64) {
        int j2 = tid >> 3, bb = tid & 7;
        int jg = (jc << 3) + j2, bg = b0 + bb;
        float gv[4];
        #pragma unroll
        for (int g = 0; g < 4; ++g)
            gv[g] = gred[(g * 8 + j2) * 8 + bb] + E[idx_s[bb] * 2048 + g * 512 + jg];
        float ig = 1.f / (1.f + expf(-gv[0]));
        float fg = 1.f / (1.f + expf(-gv[1]));
        float gg = tanhf(gv[2]);
        float og = 1.f / (1.f + expf(-gv[3]));
        float cn = fg * c1[bg * 512 + jg] + ig * gg;
        c1[bg * 512 + jg] = cn;
        h1_out[bg * 512 + jg] = og * tanhf(cn);
    }
}

__global__ __launch_bounds__(256) void lstm1_fb(
    const float* __restrict__ h1n, const float* __restrict__ h2_in,
    float* __restrict__ c2, const float* __restrict__ Wih1,
    const float* __restrict__ Whh1, const float* __restrict__ bih1,
    const float* __restrict__ bhh1, float* __restrict__ h2_out)
{
    __shared__ alignas(16) float smem[1024 * 10];
    const int tid = threadIdx.x;
    const int jc = blockIdx.x;
    const int b0 = blockIdx.y << 3;
    {
        const int dc = tid & 31, bb = tid >> 5;
        const float* xrow = h1n  + (size_t)(b0 + bb) * 512;
        const float* hrow = h2_in + (size_t)(b0 + bb) * 512;
        #pragma unroll 4
        for (int i = 0; i < 16; ++i) { int d = dc + (i << 5); smem[d * 10 + bb] = xrow[d]; }
        #pragma unroll 4
        for (int i = 0; i < 16; ++i) { int d = dc + (i << 5); smem[(512 + d) * 10 + bb] = hrow[d]; }
    }
    __syncthreads();
    const int lane = tid & 63, wave = tid >> 6;
    const int sl = lane & 15;
    const int rt = (wave << 2) | (lane >> 4);
    const int g0r = ((rt      ) >> 3) * 512 + (jc << 3) + (rt & 7);
    const int g1r = ((rt + 16 ) >> 3) * 512 + (jc << 3) + (rt & 7);
    const float* wi0 = Wih1 + (size_t)g0r * 512;
    const float* wi1 = Wih1 + (size_t)g1r * 512;
    const float* wh0 = Whh1 + (size_t)g0r * 512;
    const float* wh1 = Whh1 + (size_t)g1r * 512;
    float acc[2][8];
    #pragma unroll
    for (int r = 0; r < 2; ++r)
        #pragma unroll
        for (int q = 0; q < 8; ++q) acc[r][q] = 0.f;
    #pragma unroll 2
    for (int i = 0; i < 32; ++i) {
        int d = sl + (i << 4);
        float w0 = wi0[d], w1 = wi1[d];
        const float2* a2 = (const float2*)(smem + d * 10);
        float2 x0 = a2[0], x1 = a2[1], x2 = a2[2], x3 = a2[3];
        acc[0][0] = fmaf(w0, x0.x, acc[0][0]); acc[1][0] = fmaf(w1, x0.x, acc[1][0]);
        acc[0][1] = fmaf(w0, x0.y, acc[0][1]); acc[1][1] = fmaf(w1, x0.y, acc[1][1]);
        acc[0][2] = fmaf(w0, x1.x, acc[0][2]); acc[1][2] = fmaf(w1, x1.x, acc[1][2]);
        acc[0][3] = fmaf(w0, x1.y, acc[0][3]); acc[1][3] = fmaf(w1, x1.y, acc[1][3]);
        acc[0][4] = fmaf(w0, x2.x, acc[0][4]); acc[1][4] = fmaf(w1, x2.x, acc[1][4]);
        acc[0][5] = fmaf(w0, x2.y, acc[0][5]); acc[1][5] = fmaf(w1, x2.y, acc[1][5]);
        acc[0][6] = fmaf(w0, x3.x, acc[0][6]); acc[1][6] = fmaf(w1, x3.x, acc[1][6]);
        acc[0][7] = fmaf(w0, x3.y, acc[0][7]); acc[1][7] = fmaf(w1, x3.y, acc[1][7]);
    }
    #pragma unroll 2
    for (int i = 0; i < 32; ++i) {
        int d = sl + (i << 4);
        float w0 = wh0[d], w1 = wh1[d];
        const float2* a2 = (const float2*)(smem + (512 + d) * 10);
        float2 x0 = a2[0], x1 = a2[1], x2 = a2[2], x3 = a2[3];
        acc[0][0] = fmaf(w0, x0.x, acc[0][0]); acc[1][0] = fmaf(w1, x0.x, acc[1][0]);
        acc[0][1] = fmaf(w0, x0.y, acc[0][1]); acc[1][1] = fmaf(w1, x0.y, acc[1][1]);
        acc[0][2] = fmaf(w0, x1.x, acc[0][2]); acc[1][2] = fmaf(w1, x1.x, acc[1][2]);
        acc[0][3] = fmaf(w0, x1.y, acc[0][3]); acc[1][3] = fmaf(w1, x1.y, acc[1][3]);
        acc[0][4] = fmaf(w0, x2.x, acc[0][4]); acc[1][4] = fmaf(w1, x2.x, acc[1][4]);
        acc[0][5] = fmaf(w0, x2.y, acc[0][5]); acc[1][5] = fmaf(w1, x2.y, acc[1][5]);
        acc[0][6] = fmaf(w0, x3.x, acc[0][6]); acc[1][6] = fmaf(w1, x3.x, acc[1][6]);
        acc[0][7] = fmaf(w0, x3.y, acc[0][7]); acc[1][7] = fmaf(w1, x3.y, acc[1][7]);
    }
    float* af = &acc[0][0];
    #pragma unroll
    for (int mk = 1; mk <= 8; mk <<= 1)
        #pragma unroll
        for (int k = 0; k < 16; ++k) af[k] += __shfl_xor(af[k], mk);
    __syncthreads();
    float* gred = smem;
    if (sl == 0) {
        #pragma unroll
        for (int q = 0; q < 8; ++q) {
            gred[(rt     ) * 8 + q] = acc[0][q];
            gred[(rt + 16) * 8 + q] = acc[1][q];
        }
    }
    __syncthreads();
    if (tid < 64) {
        int j2 = tid >> 3, bb = tid & 7;
        int jg = (jc << 3) + j2, bg = b0 + bb;
        float gv[4];
        #pragma unroll
        for (int g = 0; g < 4; ++g)
            gv[g] = gred[(g * 8 + j2) * 8 + bb] + bih1[g * 512 + jg] + bhh1[g * 512 + jg];
        float ig = 1.f / (1.f + expf(-gv[0]));
        float fg = 1.f / (1.f + expf(-gv[1]));
        float gg = tanhf(gv[2]);
        float og = 1.f / (1.f + expf(-gv[3]));
        float cn = fg * c2[bg * 512 + jg] + ig * gg;
        c2[bg * 512 + jg] = cn;
        h2_out[bg * 512 + jg] = og * tanhf(cn);
    }
}

__global__ __launch_bounds__(256) void tail_fb(
    const float* __restrict__ h2f, const float* __restrict__ Wl,
    const float* __restrict__ bl, const int* __restrict__ tgt,
    float* __restrict__ out)
{
    __shared__ float q_s[512];
    __shared__ float lg[3];
    const int b = blockIdx.x, tid = threadIdx.x;
    q_s[tid]       = h2f[b * 512 + tid];
    q_s[tid + 256] = h2f[b * 512 + 256 + tid];
    __syncthreads();
    if (tid < 192) {
        int v = tid >> 6, lane = tid & 63;
        float p = 0.f;
        #pragma unroll
        for (int j = 0; j < 8; ++j)
            p += q_s[lane * 8 + j] * Wl[v * 512 + lane * 8 + j];
        for (int off = 32; off; off >>= 1) p += __shfl_xor(p, off);
        if (lane == 0) lg[v] = p + bl[v];
    }
    __syncthreads();
    if (tid == 0) {
        float m = fmaxf(lg[0], fmaxf(lg[1], lg[2]));
        float e0 = expf(lg[0] - m), e1 = expf(lg[1] - m), e2 = expf(lg[2] - m);
        float ls = logf(e0 + e1 + e2);
        float* o = out + ((size_t)b * NT + (NT - 1)) * 3;
        o[0] = lg[0] - m - ls; o[1] = lg[1] - m - ls; o[2] = lg[2] - m - ls;
    }
    for (int i = tid; i < NT; i += 256)
        out[NB * NT * 3 + b * NT + i] = (float)tgt[b * NT + i];
}

// ---------------------------------------------------------------- launch
extern "C" void kernel_launch(void* const* d_in, const int* in_sizes, int n_in,
                              void* d_out, int out_size, void* d_ws, size_t ws_size,
                              hipStream_t stream)
{
    (void)in_sizes; (void)n_in; (void)out_size; (void)ws_size;
    const float* ctx  = (const float*)d_in[0];
    const int*   tgt  = (const int*)d_in[1];
    const float* h1_0 = (const float*)d_in[3];
    const float* c1_0 = (const float*)d_in[4];
    const float* h2_0 = (const float*)d_in[5];
    const float* c2_0 = (const float*)d_in[6];
    const float* emb  = (const float*)d_in[7];
    const float* Wih0 = (const float*)d_in[8];
    const float* Whh0 = (const float*)d_in[9];
    const float* bih0 = (const float*)d_in[10];
    const float* bhh0 = (const float*)d_in[11];
    const float* Wih1 = (const float*)d_in[12];
    const float* Whh1 = (const float*)d_in[13];
    const float* bih1 = (const float*)d_in[14];
    const float* bhh1 = (const float*)d_in[15];
    const float* Wl   = (const float*)d_in[16];
    const float* bl   = (const float*)d_in[17];
    float* out = (float*)d_out;

    float* f = (float*)d_ws;
    float* h1a   = f;              float* h1b = f + 32768;
    float* h2a   = f + 65536;      float* h2b = f + 98304;
    float* c1    = f + 131072;     float* c2  = f + 163840;
    float* E     = f + 196608;     // 3*2048
    float* pm    = f + 202752;     // 512
    float* pl    = f + 203264;     // 512
    float* pacc  = f + 203776;     // 512*1024 (coop uses 256*1024 of it)
    float* algn  = f + 728064;     // 64*1024
    int*   idx   = (int*)(f + 793600);   // 64
    int*   cnt   = idx + 64;             // 64
    int*   bar   = cnt + 64;             // 512 (leaves 0..255, root 256, flag 288)

    init_kernel<<<128, 256, 0, stream>>>(h1_0, c1_0, h2_0, c2_0, tgt, h1a, c1, h2a, c2,
                                         idx, cnt, bar);
    eproj_kernel<<<24, 256, 0, stream>>>(emb, Wih0, bih0, bhh0, E);

    DecP p;
    p.ctx = ctx; p.tgt = tgt;
    p.Wih0 = Wih0; p.Whh0 = Whh0; p.Wih1 = Wih1; p.Whh1 = Whh1;
    p.bih1 = bih1; p.bhh1 = bhh1; p.Wl = Wl; p.bl = bl;
    p.out = out;
    p.h1a = h1a; p.h1b = h1b; p.h2a = h2a; p.h2b = h2b;
    p.c1 = c1; p.c2 = c2; p.E = E;
    p.pm = pm; p.pl = pl; p.pacc = pacc; p.algn = algn;
    p.idx = idx; p.cnt = cnt; p.bar = bar;

    void* args[] = { &p };
    hipError_t err = hipLaunchCooperativeKernel((const void*)decoder_persist,
                                                dim3(256), dim3(512), args, 0, stream);
    if (err != hipSuccess) {
        (void)hipGetLastError();   // clear error state; run verified fallback path
        for (int t = 0; t < NT; ++t) {
            float* h1i = (t & 1) ? h1b : h1a;  float* h1o = (t & 1) ? h1a : h1b;
            float* h2i = (t & 1) ? h2b : h2a;  float* h2o = (t & 1) ? h2a : h2b;
            attn_fb<<<dim3(NCHF, NB), 256, 0, stream>>>(ctx, h2i, Wl, bl, pm, pl, pacc,
                                                        algn, cnt, idx, out, t);
            lstm0_fb<<<dim3(64, 8), 256, 0, stream>>>(algn, h1i, c1, E, idx, Wih0, Whh0, h1o);
            lstm1_fb<<<dim3(64, 8), 256, 0, stream>>>(h1o, h2i, c2, Wih1, Whh1, bih1, bhh1, h2o);
        }
        tail_fb<<<NB, 256, 0, stream>>>(h2a, Wl, bl, tgt, out);
    }
}

// Round 5
// 29262.189 us; speedup vs baseline: 2.4431x; 1.4806x over previous
//
#include <hip/hip_runtime.h>
#include <math.h>

// Persistent cooperative decoder: 500 steps of (attention -> lstm0 -> lstm1),
// 256 blocks x 512 threads, custom 2-level monotone grid barrier.
// R5: ALL cross-block communication (h1/h2/align/pacc/pm/pl/idx) goes through
// agent-scope relaxed atomics (sc0 sc1 -> bypass L1/L2, coherent at L3). No
// __threadfence anywhere in the persistent kernel -> no buffer_inv/buffer_wbl2
// -> weights stay L2-resident across phases (R4's fences wiped L2 ~2000x/step).
// c1/c2 are block-local (same block reads+writes every step) -> normal cached.
// Fallback: if hipLaunchCooperativeKernel is rejected, run the round-1
// verified per-step kernel path (slower but correct).

#define NB 64
#define NS 500
#define NT 500

// ------------------------------------------------- scoped access helpers
__device__ __forceinline__ float2 ld_f2(const float* p) {
    unsigned long long u = __hip_atomic_load((unsigned long long*)p,
        __ATOMIC_RELAXED, __HIP_MEMORY_SCOPE_AGENT);
    union { unsigned long long u; float2 f; } c; c.u = u; return c.f;
}
__device__ __forceinline__ void st_f2(float* p, float2 v) {
    union { float2 f; unsigned long long u; } c; c.f = v;
    __hip_atomic_store((unsigned long long*)p, c.u,
        __ATOMIC_RELAXED, __HIP_MEMORY_SCOPE_AGENT);
}
__device__ __forceinline__ float ld_f(const float* p) {
    return __hip_atomic_load((float*)p, __ATOMIC_RELAXED, __HIP_MEMORY_SCOPE_AGENT);
}
__device__ __forceinline__ void st_f(float* p, float v) {
    __hip_atomic_store(p, v, __ATOMIC_RELAXED, __HIP_MEMORY_SCOPE_AGENT);
}
__device__ __forceinline__ int ld_i(const int* p) {
    return __hip_atomic_load((int*)p, __ATOMIC_RELAXED, __HIP_MEMORY_SCOPE_AGENT);
}
__device__ __forceinline__ void st_i(int* p, int v) {
    __hip_atomic_store(p, v, __ATOMIC_RELAXED, __HIP_MEMORY_SCOPE_AGENT);
}

struct DecP {
    const float* ctx; const int* tgt;
    const float* Wih0; const float* Whh0;
    const float* Wih1; const float* Whh1;
    const float* bih1; const float* bhh1;
    const float* Wl;   const float* bl;
    float* out;
    float* h1a; float* h1b; float* h2a; float* h2b;
    float* c1;  float* c2;  float* E;
    float* pm;  float* pl;  float* pacc; float* algn;
    int* idx;   int* cnt;   int* bar;
};

// Two-level grid barrier: leaves bar[(blk&7)*32], root bar[256], flag bar[288].
// Monotone counters; gen is the 1-based barrier index. No fences: producers'
// comm writes are sc1-scoped and drained by the __syncthreads (compiler emits
// s_waitcnt vmcnt(0) before s_barrier); consumers' comm reads are sc1-scoped.
__device__ __forceinline__ void fast_bar(int* bar, int gen)
{
    __syncthreads();
    if (threadIdx.x == 0) {
        int li = (blockIdx.x & 7) * 32;
        int a = __hip_atomic_fetch_add(&bar[li], 1, __ATOMIC_RELAXED, __HIP_MEMORY_SCOPE_AGENT);
        if (a == gen * 32 - 1) {
            int r = __hip_atomic_fetch_add(&bar[256], 1, __ATOMIC_RELAXED, __HIP_MEMORY_SCOPE_AGENT);
            if (r == gen * 8 - 1)
                __hip_atomic_store(&bar[288], gen, __ATOMIC_RELAXED, __HIP_MEMORY_SCOPE_AGENT);
        }
        while (__hip_atomic_load(&bar[288], __ATOMIC_RELAXED, __HIP_MEMORY_SCOPE_AGENT) < gen)
            __builtin_amdgcn_s_sleep(2);
    }
    __syncthreads();
}

// ---------------------------------------------------------------- init
__global__ __launch_bounds__(256) void init_kernel(
    const float* __restrict__ h1_0, const float* __restrict__ c1_0,
    const float* __restrict__ h2_0, const float* __restrict__ c2_0,
    const int* __restrict__ tgt,
    float* __restrict__ h1a, float* __restrict__ c1,
    float* __restrict__ h2a, float* __restrict__ c2,
    int* __restrict__ idx, int* __restrict__ cnt, int* __restrict__ bar)
{
    int gid = blockIdx.x * 256 + threadIdx.x;   // grid 128 -> 32768
    h1a[gid] = h1_0[gid];
    c1[gid]  = c1_0[gid];
    h2a[gid] = h2_0[gid];
    c2[gid]  = c2_0[gid];
    if (gid < NB) { idx[gid] = tgt[gid * NT]; cnt[gid] = 0; }
    if (gid < 512) bar[gid] = 0;
}

// ------------------------------------------------- E = emb @ W_ih0[:, :512].T + b_ih0 + b_hh0
__global__ __launch_bounds__(256) void eproj_kernel(
    const float* __restrict__ emb, const float* __restrict__ Wih0,
    const float* __restrict__ bih0, const float* __restrict__ bhh0,
    float* __restrict__ E)
{
    int gid = blockIdx.x * 256 + threadIdx.x;   // grid 24 -> 6144 = 3*2048
    int v = gid >> 11, g = gid & 2047;
    const float4* wr = (const float4*)(Wih0 + (size_t)g * 1536);
    const float4* er = (const float4*)(emb + v * 512);
    float s = bih0[g] + bhh0[g];
    #pragma unroll 4
    for (int i = 0; i < 128; ++i) {
        float4 w = wr[i], e = er[i];
        s += w.x*e.x + w.y*e.y + w.z*e.z + w.w*e.w;
    }
    E[v * 2048 + g] = s;
}

// ---------------------------------------------------------------- persistent decoder
__global__ __launch_bounds__(512, 2) void decoder_persist(DecP P)
{
    __shared__ float smem[14592];   // 58368 B
    __shared__ float wm[8], wls[8];
    __shared__ float lg[3];
    __shared__ int   is_last;
    __shared__ int   idx_s[8];

    const int tid  = threadIdx.x;
    const int blk  = blockIdx.x;
    const int lane = tid & 63, wave = tid >> 6;

    const int b_at = blk & 63, ch = blk >> 6;   // attention: 64 b x 4 chunks
    const int jc2  = blk & 31, bg = blk >> 5;   // gemm: 32 j-chunks(16j) x 8 b-groups

    float* h1i = P.h1a; float* h1o = P.h1b;
    float* h2i = P.h2a; float* h2o = P.h2b;
    int gen = 0;

    #pragma unroll 1
    for (int t = 0; t < NT; ++t) {
        // ================= Phase A: logits(t-1) + attention =================
        {
            float* q_s  = smem;          // 512
            float* wacc = smem + 512;    // 8*1024
            if (tid < 256)
                ((float2*)q_s)[tid] = ld_f2(h2i + b_at * 512 + tid * 2);
            __syncthreads();

            if (ch == 0 && t > 0) {      // block-uniform branch
                if (tid < 192) {
                    int v = tid >> 6;
                    float p = 0.f;
                    #pragma unroll
                    for (int j = 0; j < 8; ++j)
                        p += q_s[lane * 8 + j] * P.Wl[v * 512 + lane * 8 + j];
                    #pragma unroll
                    for (int off = 32; off; off >>= 1) p += __shfl_xor(p, off);
                    if (lane == 0) lg[v] = p + P.bl[v];
                }
                __syncthreads();
                if (tid == 0) {
                    float m = fmaxf(lg[0], fmaxf(lg[1], lg[2]));
                    float e0 = expf(lg[0] - m), e1 = expf(lg[1] - m), e2 = expf(lg[2] - m);
                    float ls = logf(e0 + e1 + e2);
                    float* o = P.out + ((size_t)b_at * NT + (t - 1)) * 3;
                    o[0] = lg[0] - m - ls; o[1] = lg[1] - m - ls; o[2] = lg[2] - m - ls;
                    int am = 0;
                    if (lg[1] > lg[am]) am = 1;
                    if (lg[2] > lg[am]) am = 2;
                    st_i(P.idx + b_at, am);
                }
            }

            const int s0 = ch * 125;
            const int se = s0 + 125;               // 4*125 = 500 exact
            int sA = s0 + wave * 16;
            int sB = sA + 16; if (sB > se) sB = se;
            float4 q0 = ((const float4*)q_s)[lane];
            float4 q1 = ((const float4*)q_s)[64 + lane];
            float m = -INFINITY, l = 0.f;
            float4 a0 = {0,0,0,0}, a1 = {0,0,0,0}, a2 = {0,0,0,0}, a3 = {0,0,0,0};

            for (int s = sA; s < sB; s += 4) {
                float4 rr[4][4];
                #pragma unroll
                for (int k = 0; k < 4; ++k) {
                    int ridx = (s + k < sB) ? s + k : s;
                    const float4* rp = (const float4*)(P.ctx + ((size_t)b_at * NS + ridx) * 1024);
                    rr[k][0] = rp[lane];       rr[k][1] = rp[64 + lane];
                    rr[k][2] = rp[128 + lane]; rr[k][3] = rp[192 + lane];
                }
                float p[4];
                #pragma unroll
                for (int k = 0; k < 4; ++k) {
                    float4 c0 = rr[k][0], c1 = rr[k][1], c2 = rr[k][2], c3 = rr[k][3];
                    // q = cat(h2,h2): d>=512 wraps to q0/q1
                    p[k] = c0.x*q0.x + c0.y*q0.y + c0.z*q0.z + c0.w*q0.w
                         + c1.x*q1.x + c1.y*q1.y + c1.z*q1.z + c1.w*q1.w
                         + c2.x*q0.x + c2.y*q0.y + c2.z*q0.z + c2.w*q0.w
                         + c3.x*q1.x + c3.y*q1.y + c3.z*q1.z + c3.w*q1.w;
                }
                #pragma unroll
                for (int off = 32; off; off >>= 1) {
                    p[0] += __shfl_xor(p[0], off);
                    p[1] += __shfl_xor(p[1], off);
                    p[2] += __shfl_xor(p[2], off);
                    p[3] += __shfl_xor(p[3], off);
                }
                #pragma unroll
                for (int k = 1; k < 4; ++k)
                    if (s + k >= sB) p[k] = -INFINITY;
                float mn = fmaxf(m, fmaxf(fmaxf(p[0], p[1]), fmaxf(p[2], p[3])));
                float al = expf(m - mn);        // first iter: exp(-inf)=0
                float w[4];
                #pragma unroll
                for (int k = 0; k < 4; ++k) w[k] = expf(p[k] - mn);   // invalid -> 0
                l = l * al + w[0] + w[1] + w[2] + w[3];
                #pragma unroll
                for (int c = 0; c < 4; ++c) {
                    float4* ac = (c == 0) ? &a0 : (c == 1) ? &a1 : (c == 2) ? &a2 : &a3;
                    ac->x = fmaf(w[3], rr[3][c].x, fmaf(w[2], rr[2][c].x, fmaf(w[1], rr[1][c].x, fmaf(w[0], rr[0][c].x, ac->x * al))));
                    ac->y = fmaf(w[3], rr[3][c].y, fmaf(w[2], rr[2][c].y, fmaf(w[1], rr[1][c].y, fmaf(w[0], rr[0][c].y, ac->y * al))));
                    ac->z = fmaf(w[3], rr[3][c].z, fmaf(w[2], rr[2][c].z, fmaf(w[1], rr[1][c].z, fmaf(w[0], rr[0][c].z, ac->z * al))));
                    ac->w = fmaf(w[3], rr[3][c].w, fmaf(w[2], rr[2][c].w, fmaf(w[1], rr[1][c].w, fmaf(w[0], rr[0][c].w, ac->w * al))));
                }
                m = mn;
            }
            ((float4*)wacc)[wave*256 + lane]       = a0;
            ((float4*)wacc)[wave*256 + 64 + lane]  = a1;
            ((float4*)wacc)[wave*256 + 128 + lane] = a2;
            ((float4*)wacc)[wave*256 + 192 + lane] = a3;
            if (lane == 0) { wm[wave] = m; wls[wave] = l; }
            __syncthreads();
            {   // combine 8 wave partials -> chunk partial (each thread 2 d's)
                float M = wm[0];
                #pragma unroll
                for (int w = 1; w < 8; ++w) M = fmaxf(M, wm[w]);
                float e[8]; float L = 0.f;
                #pragma unroll
                for (int w = 0; w < 8; ++w) { e[w] = expf(wm[w] - M); L += e[w] * wls[w]; }
                int d2 = tid * 2;
                float rx = 0.f, ry = 0.f;
                #pragma unroll
                for (int w = 0; w < 8; ++w) {
                    float2 x = *(float2*)&wacc[w*1024 + d2];
                    rx = fmaf(e[w], x.x, rx); ry = fmaf(e[w], x.y, ry);
                }
                st_f2(&P.pacc[((size_t)(b_at*4 + ch))*1024 + d2], make_float2(rx, ry));
                if (tid == 0) { st_f(&P.pm[b_at*4 + ch], M); st_f(&P.pl[b_at*4 + ch], L); }
            }
            __syncthreads();      // drains the scoped stores (vmcnt) wave-wide
            if (tid == 0) {
                int old = __hip_atomic_fetch_add(P.cnt + b_at, 1, __ATOMIC_RELAXED,
                                                 __HIP_MEMORY_SCOPE_AGENT);
                is_last = (old == 4*t + 3) ? 1 : 0;     // monotone counter
            }
            __syncthreads();
            if (is_last) {      // combine 4 chunks -> align[b] (scoped reads)
                float pmv[4], plv[4];
                #pragma unroll
                for (int k = 0; k < 4; ++k) { pmv[k] = ld_f(&P.pm[b_at*4 + k]); plv[k] = ld_f(&P.pl[b_at*4 + k]); }
                float M = -INFINITY;
                #pragma unroll
                for (int k = 0; k < 4; ++k) M = fmaxf(M, pmv[k]);
                float e[4]; float L = 0.f;
                #pragma unroll
                for (int k = 0; k < 4; ++k) { e[k] = expf(pmv[k] - M); L += e[k] * plv[k]; }
                float invL = 1.f / L;
                int d2 = tid * 2;
                float rx = 0.f, ry = 0.f;
                #pragma unroll
                for (int k = 0; k < 4; ++k) {
                    float2 x = ld_f2(&P.pacc[((size_t)(b_at*4 + k))*1024 + d2]);
                    rx = fmaf(e[k], x.x, rx); ry = fmaf(e[k], x.y, ry);
                }
                st_f2(&P.algn[b_at*1024 + d2], make_float2(rx*invL, ry*invL));
            }
        }
        fast_bar(P.bar, ++gen);
        // ================= Phase B: lstm0 -> h1 =================
        {
            float* x0    = smem;           // 8 b x 1536 k  [b][k]
            float* gred2 = smem + 12288;   // 8 rg x 8 kgrp x 32
            float* gred  = smem + 14336;   // 256
            if (tid < 8) idx_s[tid] = ld_i(P.idx + bg*8 + tid);
            #pragma unroll
            for (int j = 0; j < 12; ++j) {
                int i2 = tid + j*512;               // 0..6143 float2s
                int bb = i2 / 768, r = i2 - bb*768;
                int b = bg*8 + bb;
                float2 v = (r < 512) ? ld_f2(P.algn + b*1024 + r*2)
                                     : ld_f2(h1i + b*512 + (r - 512)*2);
                ((float2*)x0)[i2] = v;
            }
            __syncthreads();
            const int rg = wave;
            const int g = rg >> 1, qq = (rg & 1) * 4;
            #pragma unroll 1
            for (int p = 0; p < 2; ++p) {
                const int jc = jc2*2 + p;
                const int row0 = g*512 + jc*8 + qq;     // rows row0..row0+3
                float af[32];
                #pragma unroll
                for (int q = 0; q < 32; ++q) af[q] = 0.f;
                #pragma unroll
                for (int i = 0; i < 6; ++i) {
                    int k = i*256 + lane*4;
                    float4 w0, w1, w2, w3;
                    if (i < 4) {
                        const float* wb = P.Wih0 + (size_t)row0*1536 + 512 + k;
                        w0 = *(const float4*)(wb);
                        w1 = *(const float4*)(wb + 1536);
                        w2 = *(const float4*)(wb + 3072);
                        w3 = *(const float4*)(wb + 4608);
                    } else {
                        const float* wb = P.Whh0 + (size_t)row0*512 + (k - 1024);
                        w0 = *(const float4*)(wb);
                        w1 = *(const float4*)(wb + 512);
                        w2 = *(const float4*)(wb + 1024);
                        w3 = *(const float4*)(wb + 1536);
                    }
                    #pragma unroll
                    for (int bb = 0; bb < 8; ++bb) {
                        float4 x = *(const float4*)&x0[bb*1536 + k];
                        af[0*8+bb] = fmaf(w0.w, x.w, fmaf(w0.z, x.z, fmaf(w0.y, x.y, fmaf(w0.x, x.x, af[0*8+bb]))));
                        af[1*8+bb] = fmaf(w1.w, x.w, fmaf(w1.z, x.z, fmaf(w1.y, x.y, fmaf(w1.x, x.x, af[1*8+bb]))));
                        af[2*8+bb] = fmaf(w2.w, x.w, fmaf(w2.z, x.z, fmaf(w2.y, x.y, fmaf(w2.x, x.x, af[2*8+bb]))));
                        af[3*8+bb] = fmaf(w3.w, x.w, fmaf(w3.z, x.z, fmaf(w3.y, x.y, fmaf(w3.x, x.x, af[3*8+bb]))));
                    }
                }
                #pragma unroll
                for (int mm = 1; mm <= 4; mm <<= 1) {
                    #pragma unroll
                    for (int q = 0; q < 32; ++q) af[q] += __shfl_xor(af[q], mm);
                }
                if ((lane & 7) == 0) {
                    const int kg = lane >> 3;
                    float* gdst = gred2 + rg*256 + kg*32;
                    #pragma unroll
                    for (int q = 0; q < 8; ++q)
                        *(float4*)(gdst + q*4) = make_float4(af[q*4], af[q*4+1], af[q*4+2], af[q*4+3]);
                }
                __syncthreads();
                if (tid < 256) {
                    int rb = tid >> 3, bb = tid & 7;
                    int rg2 = rb >> 2, rr2 = rb & 3;
                    float s = 0.f;
                    #pragma unroll
                    for (int kg = 0; kg < 8; ++kg) s += gred2[rg2*256 + kg*32 + rr2*8 + bb];
                    gred[tid] = s;   // gred[(g*8+jj)*8+bb]
                }
                __syncthreads();
                if (tid < 64) {
                    int jj = tid >> 3, bb = tid & 7;
                    int j = jc*8 + jj, b = bg*8 + bb;
                    float gv[4];
                    #pragma unroll
                    for (int gg = 0; gg < 4; ++gg)
                        gv[gg] = gred[(gg*8 + jj)*8 + bb] + P.E[idx_s[bb]*2048 + gg*512 + j];
                    float ig = 1.f / (1.f + expf(-gv[0]));
                    float fg = 1.f / (1.f + expf(-gv[1]));
                    float g2 = tanhf(gv[2]);
                    float og = 1.f / (1.f + expf(-gv[3]));
                    float cn = fg * P.c1[b*512 + j] + ig * g2;   // c1: block-local, cached
                    P.c1[b*512 + j] = cn;
                    st_f(&h1o[b*512 + j], og * tanhf(cn));
                }
            }
        }
        fast_bar(P.bar, ++gen);
        // ================= Phase C: lstm1 -> h2 =================
        {
            float* x1    = smem;           // 8 b x 1024 k  [b][k]
            float* gred2 = smem + 12288;
            float* gred  = smem + 14336;
            #pragma unroll
            for (int j = 0; j < 8; ++j) {
                int i2 = tid + j*512;               // 0..4095 float2s
                int bb = i2 >> 9, r = i2 & 511;
                int b = bg*8 + bb;
                float2 v = (r < 256) ? ld_f2(h1o + b*512 + r*2)
                                     : ld_f2(h2i + b*512 + (r - 256)*2);
                ((float2*)x1)[i2] = v;
            }
            __syncthreads();
            const int rg = wave;
            const int g = rg >> 1, qq = (rg & 1) * 4;
            #pragma unroll 1
            for (int p = 0; p < 2; ++p) {
                const int jc = jc2*2 + p;
                const int row0 = g*512 + jc*8 + qq;
                float af[32];
                #pragma unroll
                for (int q = 0; q < 32; ++q) af[q] = 0.f;
                #pragma unroll
                for (int i = 0; i < 4; ++i) {
                    int k = i*256 + lane*4;
                    float4 w0, w1, w2, w3;
                    if (i < 2) {
                        const float* wb = P.Wih1 + (size_t)row0*512 + k;
                        w0 = *(const float4*)(wb);
                        w1 = *(const float4*)(wb + 512);
                        w2 = *(const float4*)(wb + 1024);
                        w3 = *(const float4*)(wb + 1536);
                    } else {
                        const float* wb = P.Whh1 + (size_t)row0*512 + (k - 512);
                        w0 = *(const float4*)(wb);
                        w1 = *(const float4*)(wb + 512);
                        w2 = *(const float4*)(wb + 1024);
                        w3 = *(const float4*)(wb + 1536);
                    }
                    #pragma unroll
                    for (int bb = 0; bb < 8; ++bb) {
                        float4 x = *(const float4*)&x1[bb*1024 + k];
                        af[0*8+bb] = fmaf(w0.w, x.w, fmaf(w0.z, x.z, fmaf(w0.y, x.y, fmaf(w0.x, x.x, af[0*8+bb]))));
                        af[1*8+bb] = fmaf(w1.w, x.w, fmaf(w1.z, x.z, fmaf(w1.y, x.y, fmaf(w1.x, x.x, af[1*8+bb]))));
                        af[2*8+bb] = fmaf(w2.w, x.w, fmaf(w2.z, x.z, fmaf(w2.y, x.y, fmaf(w2.x, x.x, af[2*8+bb]))));
                        af[3*8+bb] = fmaf(w3.w, x.w, fmaf(w3.z, x.z, fmaf(w3.y, x.y, fmaf(w3.x, x.x, af[3*8+bb]))));
                    }
                }
                #pragma unroll
                for (int mm = 1; mm <= 4; mm <<= 1) {
                    #pragma unroll
                    for (int q = 0; q < 32; ++q) af[q] += __shfl_xor(af[q], mm);
                }
                if ((lane & 7) == 0) {
                    const int kg = lane >> 3;
                    float* gdst = gred2 + rg*256 + kg*32;
                    #pragma unroll
                    for (int q = 0; q < 8; ++q)
                        *(float4*)(gdst + q*4) = make_float4(af[q*4], af[q*4+1], af[q*4+2], af[q*4+3]);
                }
                __syncthreads();
                if (tid < 256) {
                    int rb = tid >> 3, bb = tid & 7;
                    int rg2 = rb >> 2, rr2 = rb & 3;
                    float s = 0.f;
                    #pragma unroll
                    for (int kg = 0; kg < 8; ++kg) s += gred2[rg2*256 + kg*32 + rr2*8 + bb];
                    gred[tid] = s;
                }
                __syncthreads();
                if (tid < 64) {
                    int jj = tid >> 3, bb = tid & 7;
                    int j = jc*8 + jj, b = bg*8 + bb;
                    float gv[4];
                    #pragma unroll
                    for (int gg = 0; gg < 4; ++gg)
                        gv[gg] = gred[(gg*8 + jj)*8 + bb] + P.bih1[gg*512 + j] + P.bhh1[gg*512 + j];
                    float ig = 1.f / (1.f + expf(-gv[0]));
                    float fg = 1.f / (1.f + expf(-gv[1]));
                    float g2 = tanhf(gv[2]);
                    float og = 1.f / (1.f + expf(-gv[3]));
                    float cn = fg * P.c2[b*512 + j] + ig * g2;   // c2: block-local, cached
                    P.c2[b*512 + j] = cn;
                    st_f(&h2o[b*512 + j], og * tanhf(cn));
                }
            }
        }
        fast_bar(P.bar, ++gen);
        // swap state buffers
        float* tsw;
        tsw = h1i; h1i = h1o; h1o = tsw;
        tsw = h2i; h2i = h2o; h2o = tsw;
    }
    // ================= tail: logits(499) + target copy =================
    if (blk < NB) {
        const int b = blk;
        float* q_s = smem;
        if (tid < 256)
            ((float2*)q_s)[tid] = ld_f2(h2i + b * 512 + tid * 2);
        __syncthreads();
        if (tid < 192) {
            int v = tid >> 6;
            float p = 0.f;
            #pragma unroll
            for (int j = 0; j < 8; ++j)
                p += q_s[lane*8 + j] * P.Wl[v*512 + lane*8 + j];
            #pragma unroll
            for (int off = 32; off; off >>= 1) p += __shfl_xor(p, off);
            if (lane == 0) lg[v] = p + P.bl[v];
        }
        __syncthreads();
        if (tid == 0) {
            float m = fmaxf(lg[0], fmaxf(lg[1], lg[2]));
            float e0 = expf(lg[0]-m), e1 = expf(lg[1]-m), e2 = expf(lg[2]-m);
            float ls = logf(e0 + e1 + e2);
            float* o = P.out + ((size_t)b*NT + (NT-1))*3;
            o[0] = lg[0]-m-ls; o[1] = lg[1]-m-ls; o[2] = lg[2]-m-ls;
        }
        for (int i = tid; i < NT; i += 512)
            P.out[NB*NT*3 + b*NT + i] = (float)P.tgt[b*NT + i];
    }
}

// ================================================================ fallback path
// Round-1 verified per-step kernels (used only if cooperative launch is rejected).
#define NCHF 8
#define CHSF 63

__global__ __launch_bounds__(256) void attn_fb(
    const float* __restrict__ ctx, const float* __restrict__ h2_in,
    const float* __restrict__ Wl, const float* __restrict__ bl,
    float* __restrict__ pm, float* __restrict__ pl, float* __restrict__ pacc,
    float* __restrict__ align_g, int* __restrict__ cnt, int* __restrict__ idx,
    float* __restrict__ out, int t)
{
    __shared__ alignas(16) float q_s[512];
    __shared__ alignas(16) float wacc[4 * 1024];
    __shared__ float wm[4], wl_s[4];
    __shared__ float lg[3];
    __shared__ int is_last;
    const int tid = threadIdx.x;
    const int ch = blockIdx.x, b = blockIdx.y;

    q_s[tid]       = h2_in[b * 512 + tid];
    q_s[tid + 256] = h2_in[b * 512 + 256 + tid];
    __syncthreads();

    if (ch == 0 && t > 0) {
        if (tid < 192) {
            int v = tid >> 6, lane = tid & 63;
            float p = 0.f;
            #pragma unroll
            for (int j = 0; j < 8; ++j)
                p += q_s[lane * 8 + j] * Wl[v * 512 + lane * 8 + j];
            for (int off = 32; off; off >>= 1) p += __shfl_xor(p, off);
            if (lane == 0) lg[v] = p + bl[v];
        }
        __syncthreads();
        if (tid == 0) {
            float m = fmaxf(lg[0], fmaxf(lg[1], lg[2]));
            float e0 = expf(lg[0] - m), e1 = expf(lg[1] - m), e2 = expf(lg[2] - m);
            float ls = logf(e0 + e1 + e2);
            float* o = out + ((size_t)b * NT + (t - 1)) * 3;
            o[0] = lg[0] - m - ls; o[1] = lg[1] - m - ls; o[2] = lg[2] - m - ls;
            int am = 0;
            if (lg[1] > lg[am]) am = 1;
            if (lg[2] > lg[am]) am = 2;
            idx[b] = am;
        }
    }

    const int lane = tid & 63, wave = tid >> 6;
    const int s0 = ch * CHSF;
    const int s1 = (s0 + CHSF < NS) ? s0 + CHSF : NS;
    float4 q0 = ((const float4*)q_s)[lane];
    float4 q1 = ((const float4*)q_s)[64 + lane];
    float m = -INFINITY, l = 0.f;
    float4 a0 = {0,0,0,0}, a1 = {0,0,0,0}, a2 = {0,0,0,0}, a3 = {0,0,0,0};

    for (int s = s0 + wave; s < s1; s += 4) {
        const float4* crow = (const float4*)(ctx + ((size_t)b * NS + s) * 1024);
        float4 v0 = crow[lane], v1 = crow[64 + lane], v2 = crow[128 + lane], v3 = crow[192 + lane];
        float p = v0.x*q0.x + v0.y*q0.y + v0.z*q0.z + v0.w*q0.w
                + v1.x*q1.x + v1.y*q1.y + v1.z*q1.z + v1.w*q1.w
                + v2.x*q0.x + v2.y*q0.y + v2.z*q0.z + v2.w*q0.w
                + v3.x*q1.x + v3.y*q1.y + v3.z*q1.z + v3.w*q1.w;
        for (int off = 32; off; off >>= 1) p += __shfl_xor(p, off);
        float mn = fmaxf(m, p);
        float al = expf(m - mn);
        float w  = expf(p - mn);
        l = l * al + w;
        a0.x = a0.x*al + w*v0.x; a0.y = a0.y*al + w*v0.y; a0.z = a0.z*al + w*v0.z; a0.w = a0.w*al + w*v0.w;
        a1.x = a1.x*al + w*v1.x; a1.y = a1.y*al + w*v1.y; a1.z = a1.z*al + w*v1.z; a1.w = a1.w*al + w*v1.w;
        a2.x = a2.x*al + w*v2.x; a2.y = a2.y*al + w*v2.y; a2.z = a2.z*al + w*v2.z; a2.w = a2.w*al + w*v2.w;
        a3.x = a3.x*al + w*v3.x; a3.y = a3.y*al + w*v3.y; a3.z = a3.z*al + w*v3.z; a3.w = a3.w*al + w*v3.w;
        m = mn;
    }
    ((float4*)wacc)[wave * 256 + lane]       = a0;
    ((float4*)wacc)[wave * 256 + 64 + lane]  = a1;
    ((float4*)wacc)[wave * 256 + 128 + lane] = a2;
    ((float4*)wacc)[wave * 256 + 192 + lane] = a3;
    if (lane == 0) { wm[wave] = m; wl_s[wave] = l; }
    __syncthreads();
    {
        float M = fmaxf(fmaxf(wm[0], wm[1]), fmaxf(wm[2], wm[3]));
        float e0 = expf(wm[0]-M), e1 = expf(wm[1]-M), e2 = expf(wm[2]-M), e3 = expf(wm[3]-M);
        float L = e0*wl_s[0] + e1*wl_s[1] + e2*wl_s[2] + e3*wl_s[3];
        const float4* w4 = (const float4*)wacc;
        float4 x0 = w4[tid], x1 = w4[256 + tid], x2 = w4[512 + tid], x3 = w4[768 + tid];
        float4 r;
        r.x = e0*x0.x + e1*x1.x + e2*x2.x + e3*x3.x;
        r.y = e0*x0.y + e1*x1.y + e2*x2.y + e3*x3.y;
        r.z = e0*x0.z + e1*x1.z + e2*x2.z + e3*x3.z;
        r.w = e0*x0.w + e1*x1.w + e2*x2.w + e3*x3.w;
        ((float4*)pacc)[(b * NCHF + ch) * 256 + tid] = r;
        if (tid == 0) { pm[b * NCHF + ch] = M; pl[b * NCHF + ch] = L; }
    }
    __syncthreads();
    if (tid == 0) {
        __threadfence();
        int old = __hip_atomic_fetch_add(cnt + b, 1, __ATOMIC_ACQ_REL, __HIP_MEMORY_SCOPE_AGENT);
        is_last = (old == NCHF * t + (NCHF - 1)) ? 1 : 0;
    }
    __syncthreads();
    if (is_last) {
        float M = -INFINITY;
        #pragma unroll
        for (int k = 0; k < NCHF; ++k) M = fmaxf(M, pm[b * NCHF + k]);
        float e[NCHF]; float L = 0.f;
        #pragma unroll
        for (int k = 0; k < NCHF; ++k) { e[k] = expf(pm[b * NCHF + k] - M); L += e[k] * pl[b * NCHF + k]; }
        float invL = 1.f / L;
        const float4* p4 = (const float4*)pacc;
        float4 r = {0,0,0,0};
        #pragma unroll
        for (int k = 0; k < NCHF; ++k) {
            float4 x = p4[(b * NCHF + k) * 256 + tid];
            r.x += e[k]*x.x; r.y += e[k]*x.y; r.z += e[k]*x.z; r.w += e[k]*x.w;
        }
        r.x *= invL; r.y *= invL; r.z *= invL; r.w *= invL;
        ((float4*)align_g)[b * 256 + tid] = r;
    }
}

__global__ __launch_bounds__(256) void lstm0_fb(
    const float* __restrict__ align_g, const float* __restrict__ h1_in,
    float* __restrict__ c1, const float* __restrict__ E,
    const int* __restrict__ idx, const float* __restrict__ Wih0,
    const float* __restrict__ Whh0, float* __restrict__ h1_out)
{
    __shared__ alignas(16) float smem[1536 * 10];
    __shared__ int idx_s[8];
    const int tid = threadIdx.x;
    const int jc = blockIdx.x;
    const int b0 = blockIdx.y << 3;
    {
        const int dc = tid & 31, bb = tid >> 5;
        const float* arow = align_g + (size_t)(b0 + bb) * 1024;
        const float* hrow = h1_in + (size_t)(b0 + bb) * 512;
        #pragma unroll 4
        for (int i = 0; i < 32; ++i) { int d = dc + (i << 5); smem[d * 10 + bb] = arow[d]; }
        #pragma unroll 4
        for (int i = 0; i < 16; ++i) { int d = dc + (i << 5); smem[(1024 + d) * 10 + bb] = hrow[d]; }
        if (tid < 8) idx_s[tid] = idx[b0 + tid];
    }
    __syncthreads();
    const int lane = tid & 63, wave = tid >> 6;
    const int sl = lane & 15;
    const int rt = (wave << 2) | (lane >> 4);
    const int g0r = ((rt      ) >> 3) * 512 + (jc << 3) + (rt & 7);
    const int g1r = ((rt + 16 ) >> 3) * 512 + (jc << 3) + (rt & 7);
    const float* wa0 = Wih0 + (size_t)g0r * 1536 + 512;
    const float* wa1 = Wih0 + (size_t)g1r * 1536 + 512;
    const float* wh0 = Whh0 + (size_t)g0r * 512;
    const float* wh1 = Whh0 + (size_t)g1r * 512;
    float acc[2][8];
    #pragma unroll
    for (int r = 0; r < 2; ++r)
        #pragma unroll
        for (int q = 0; q < 8; ++q) acc[r][q] = 0.f;
    #pragma unroll 2
    for (int i = 0; i < 64; ++i) {
        int d = sl + (i << 4);
        float w0 = wa0[d], w1 = wa1[d];
        const float2* a2 = (const float2*)(smem + d * 10);
        float2 x0 = a2[0], x1 = a2[1], x2 = a2[2], x3 = a2[3];
        acc[0][0] = fmaf(w0, x0.x, acc[0][0]); acc[1][0] = fmaf(w1, x0.x, acc[1][0]);
        acc[0][1] = fmaf(w0, x0.y, acc[0][1]); acc[1][1] = fmaf(w1, x0.y, acc[1][1]);
        acc[0][2] = fmaf(w0, x1.x, acc[0][2]); acc[1][2] = fmaf(w1, x1.x, acc[1][2]);
        acc[0][3] = fmaf(w0, x1.y, acc[0][3]); acc[1][3] = fmaf(w1, x1.y, acc[1][3]);
        acc[0][4] = fmaf(w0, x2.x, acc[0][4]); acc[1][4] = fmaf(w1, x2.x, acc[1][4]);
        acc[0][5] = fmaf(w0, x2.y, acc[0][5]); acc[1][5] = fmaf(w1, x2.y, acc[1][5]);
        acc[0][6] = fmaf(w0, x3.x, acc[0][6]); acc[1][6] = fmaf(w1, x3.x, acc[1][6]);
        acc[0][7] = fmaf(w0, x3.y, acc[0][7]); acc[1][7] = fmaf(w1, x3.y, acc[1][7]);
    }
    #pragma unroll 2
    for (int i = 0; i < 32; ++i) {
        int d = sl + (i << 4);
        float w0 = wh0[d], w1 = wh1[d];
        const float2* a2 = (const float2*)(smem + (1024 + d) * 10);
        float2 x0 = a2[0], x1 = a2[1], x2 = a2[2], x3 = a2[3];
        acc[0][0] = fmaf(w0, x0.x, acc[0][0]); acc[1][0] = fmaf(w1, x0.x, acc[1][0]);
        acc[0][1] = fmaf(w0, x0.y, acc[0][1]); acc[1][1] = fmaf(w1, x0.y, acc[1][1]);
        acc[0][2] = fmaf(w0, x1.x, acc[0][2]); acc[1][2] = fmaf(w1, x1.x, acc[1][2]);
        acc[0][3] = fmaf(w0, x1.y, acc[0][3]); acc[1][3] = fmaf(w1, x1.y, acc[1][3]);
        acc[0][4] = fmaf(w0, x2.x, acc[0][4]); acc[1][4] = fmaf(w1, x2.x, acc[1][4]);
        acc[0][5] = fmaf(w0, x2.y, acc[0][5]); acc[1][5] = fmaf(w1, x2.y, acc[1][5]);
        acc[0][6] = fmaf(w0, x3.x, acc[0][6]); acc[1][6] = fmaf(w1, x3.x, acc[1][6]);
        acc[0][7] = fmaf(w0, x3.y, acc[0][7]); acc[1][7] = fmaf(w1, x3.y, acc[1][7]);
    }
    float* af = &acc[0][0];
    #pragma unroll
    for (int mk = 1; mk <= 8; mk <<= 1)
        #pragma unroll
        for (int k = 0; k < 16; ++k) af[k] += __shfl_xor(af[k], mk);
    __syncthreads();
    float* gred = smem;
    if (sl == 0) {
        #pragma unroll
        for (int q = 0; q < 8; ++q) {
            gred[(rt     ) * 8 + q] = acc[0][q];
            gred[(rt + 16) * 8 + q] = acc[1][q];
        }
    }
    __syncthreads();
    if (tid < 64) {
        int j2 = tid >> 3, bb = tid & 7;
        int jg = (jc << 3) + j2, bg = b0 + bb;
        float gv[4];
        #pragma unroll
        for (int g = 0; g < 4; ++g)
            gv[g] = gred[(g * 8 + j2) * 8 + bb] + E[idx_s[bb] * 2048 + g * 512 + jg];
        float ig = 1.f / (1.f + expf(-gv[0]));
        float fg = 1.f / (1.f + expf(-gv[1]));
        float gg = tanhf(gv[2]);
        float og = 1.f / (1.f + expf(-gv[3]));
        float cn = fg * c1[bg * 512 + jg] + ig * gg;
        c1[bg * 512 + jg] = cn;
        h1_out[bg * 512 + jg] = og * tanhf(cn);
    }
}

__global__ __launch_bounds__(256) void lstm1_fb(
    const float* __restrict__ h1n, const float* __restrict__ h2_in,
    float* __restrict__ c2, const float* __restrict__ Wih1,
    const float* __restrict__ Whh1, const float* __restrict__ bih1,
    const float* __restrict__ bhh1, float* __restrict__ h2_out)
{
    __shared__ alignas(16) float smem[1024 * 10];
    const int tid = threadIdx.x;
    const int jc = blockIdx.x;
    const int b0 = blockIdx.y << 3;
    {
        const int dc = tid & 31, bb = tid >> 5;
        const float* xrow = h1n  + (size_t)(b0 + bb) * 512;
        const float* hrow = h2_in + (size_t)(b0 + bb) * 512;
        #pragma unroll 4
        for (int i = 0; i < 16; ++i) { int d = dc + (i << 5); smem[d * 10 + bb] = xrow[d]; }
        #pragma unroll 4
        for (int i = 0; i < 16; ++i) { int d = dc + (i << 5); smem[(512 + d) * 10 + bb] = hrow[d]; }
    }
    __syncthreads();
    const int lane = tid & 63, wave = tid >> 6;
    const int sl = lane & 15;
    const int rt = (wave << 2) | (lane >> 4);
    const int g0r = ((rt      ) >> 3) * 512 + (jc << 3) + (rt & 7);
    const int g1r = ((rt + 16 ) >> 3) * 512 + (jc << 3) + (rt & 7);
    const float* wi0 = Wih1 + (size_t)g0r * 512;
    const float* wi1 = Wih1 + (size_t)g1r * 512;
    const float* wh0 = Whh1 + (size_t)g0r * 512;
    const float* wh1 = Whh1 + (size_t)g1r * 512;
    float acc[2][8];
    #pragma unroll
    for (int r = 0; r < 2; ++r)
        #pragma unroll
        for (int q = 0; q < 8; ++q) acc[r][q] = 0.f;
    #pragma unroll 2
    for (int i = 0; i < 32; ++i) {
        int d = sl + (i << 4);
        float w0 = wi0[d], w1 = wi1[d];
        const float2* a2 = (const float2*)(smem + d * 10);
        float2 x0 = a2[0], x1 = a2[1], x2 = a2[2], x3 = a2[3];
        acc[0][0] = fmaf(w0, x0.x, acc[0][0]); acc[1][0] = fmaf(w1, x0.x, acc[1][0]);
        acc[0][1] = fmaf(w0, x0.y, acc[0][1]); acc[1][1] = fmaf(w1, x0.y, acc[1][1]);
        acc[0][2] = fmaf(w0, x1.x, acc[0][2]); acc[1][2] = fmaf(w1, x1.x, acc[1][2]);
        acc[0][3] = fmaf(w0, x1.y, acc[0][3]); acc[1][3] = fmaf(w1, x1.y, acc[1][3]);
        acc[0][4] = fmaf(w0, x2.x, acc[0][4]); acc[1][4] = fmaf(w1, x2.x, acc[1][4]);
        acc[0][5] = fmaf(w0, x2.y, acc[0][5]); acc[1][5] = fmaf(w1, x2.y, acc[1][5]);
        acc[0][6] = fmaf(w0, x3.x, acc[0][6]); acc[1][6] = fmaf(w1, x3.x, acc[1][6]);
        acc[0][7] = fmaf(w0, x3.y, acc[0][7]); acc[1][7] = fmaf(w1, x3.y, acc[1][7]);
    }
    #pragma unroll 2
    for (int i = 0; i < 32; ++i) {
        int d = sl + (i << 4);
        float w0 = wh0[d], w1 = wh1[d];
        const float2* a2 = (const float2*)(smem + (512 + d) * 10);
        float2 x0 = a2[0], x1 = a2[1], x2 = a2[2], x3 = a2[3];
        acc[0][0] = fmaf(w0, x0.x, acc[0][0]); acc[1][0] = fmaf(w1, x0.x, acc[1][0]);
        acc[0][1] = fmaf(w0, x0.y, acc[0][1]); acc[1][1] = fmaf(w1, x0.y, acc[1][1]);
        acc[0][2] = fmaf(w0, x1.x, acc[0][2]); acc[1][2] = fmaf(w1, x1.x, acc[1][2]);
        acc[0][3] = fmaf(w0, x1.y, acc[0][3]); acc[1][3] = fmaf(w1, x1.y, acc[1][3]);
        acc[0][4] = fmaf(w0, x2.x, acc[0][4]); acc[1][4] = fmaf(w1, x2.x, acc[1][4]);
        acc[0][5] = fmaf(w0, x2.y, acc[0][5]); acc[1][5] = fmaf(w1, x2.y, acc[1][5]);
        acc[0][6] = fmaf(w0, x3.x, acc[0][6]); acc[1][6] = fmaf(w1, x3.x, acc[1][6]);
        acc[0][7] = fmaf(w0, x3.y, acc[0][7]); acc[1][7] = fmaf(w1, x3.y, acc[1][7]);
    }
    float* af = &acc[0][0];
    #pragma unroll
    for (int mk = 1; mk <= 8; mk <<= 1)
        #pragma unroll
        for (int k = 0; k < 16; ++k) af[k] += __shfl_xor(af[k], mk);
    __syncthreads();
    float* gred = smem;
    if (sl == 0) {
        #pragma unroll
        for (int q = 0; q < 8; ++q) {
            gred[(rt     ) * 8 + q] = acc[0][q];
            gred[(rt + 16) * 8 + q] = acc[1][q];
        }
    }
    __syncthreads();
    if (tid < 64) {
        int j2 = tid >> 3, bb = tid & 7;
        int jg = (jc << 3) + j2, bg = b0 + bb;
        float gv[4];
        #pragma unroll
        for (int g = 0; g < 4; ++g)
            gv[g] = gred[(g * 8 + j2) * 8 + bb] + bih1[g * 512 + jg] + bhh1[g * 512 + jg];
        float ig = 1.f / (1.f + expf(-gv[0]));
        float fg = 1.f / (1.f + expf(-gv[1]));
        float gg = tanhf(gv[2]);
        float og = 1.f / (1.f + expf(-gv[3]));
        float cn = fg * c2[bg * 512 + jg] + ig * gg;
        c2[bg * 512 + jg] = cn;
        h2_out[bg * 512 + jg] = og * tanhf(cn);
    }
}

__global__ __launch_bounds__(256) void tail_fb(
    const float* __restrict__ h2f, const float* __restrict__ Wl,
    const float* __restrict__ bl, const int* __restrict__ tgt,
    float* __restrict__ out)
{
    __shared__ float q_s[512];
    __shared__ float lg[3];
    const int b = blockIdx.x, tid = threadIdx.x;
    q_s[tid]       = h2f[b * 512 + tid];
    q_s[tid + 256] = h2f[b * 512 + 256 + tid];
    __syncthreads();
    if (tid < 192) {
        int v = tid >> 6, lane = tid & 63;
        float p = 0.f;
        #pragma unroll
        for (int j = 0; j < 8; ++j)
            p += q_s[lane * 8 + j] * Wl[v * 512 + lane * 8 + j];
        for (int off = 32; off; off >>= 1) p += __shfl_xor(p, off);
        if (lane == 0) lg[v] = p + bl[v];
    }
    __syncthreads();
    if (tid == 0) {
        float m = fmaxf(lg[0], fmaxf(lg[1], lg[2]));
        float e0 = expf(lg[0] - m), e1 = expf(lg[1] - m), e2 = expf(lg[2] - m);
        float ls = logf(e0 + e1 + e2);
        float* o = out + ((size_t)b * NT + (NT - 1)) * 3;
        o[0] = lg[0] - m - ls; o[1] = lg[1] - m - ls; o[2] = lg[2] - m - ls;
    }
    for (int i = tid; i < NT; i += 256)
        out[NB * NT * 3 + b * NT + i] = (float)tgt[b * NT + i];
}

// ---------------------------------------------------------------- launch
extern "C" void kernel_launch(void* const* d_in, const int* in_sizes, int n_in,
                              void* d_out, int out_size, void* d_ws, size_t ws_size,
                              hipStream_t stream)
{
    (void)in_sizes; (void)n_in; (void)out_size; (void)ws_size;
    const float* ctx  = (const float*)d_in[0];
    const int*   tgt  = (const int*)d_in[1];
    const float* h1_0 = (const float*)d_in[3];
    const float* c1_0 = (const float*)d_in[4];
    const float* h2_0 = (const float*)d_in[5];
    const float* c2_0 = (const float*)d_in[6];
    const float* emb  = (const float*)d_in[7];
    const float* Wih0 = (const float*)d_in[8];
    const float* Whh0 = (const float*)d_in[9];
    const float* bih0 = (const float*)d_in[10];
    const float* bhh0 = (const float*)d_in[11];
    const float* Wih1 = (const float*)d_in[12];
    const float* Whh1 = (const float*)d_in[13];
    const float* bih1 = (const float*)d_in[14];
    const float* bhh1 = (const float*)d_in[15];
    const float* Wl   = (const float*)d_in[16];
    const float* bl   = (const float*)d_in[17];
    float* out = (float*)d_out;

    float* f = (float*)d_ws;
    float* h1a   = f;              float* h1b = f + 32768;
    float* h2a   = f + 65536;      float* h2b = f + 98304;
    float* c1    = f + 131072;     float* c2  = f + 163840;
    float* E     = f + 196608;     // 3*2048
    float* pm    = f + 202752;     // 512
    float* pl    = f + 203264;     // 512
    float* pacc  = f + 203776;     // 512*1024 (coop uses 256*1024 of it)
    float* algn  = f + 728064;     // 64*1024
    int*   idx   = (int*)(f + 793600);   // 64
    int*   cnt   = idx + 64;             // 64
    int*   bar   = cnt + 64;             // 512 (leaves 0..255, root 256, flag 288)

    init_kernel<<<128, 256, 0, stream>>>(h1_0, c1_0, h2_0, c2_0, tgt, h1a, c1, h2a, c2,
                                         idx, cnt, bar);
    eproj_kernel<<<24, 256, 0, stream>>>(emb, Wih0, bih0, bhh0, E);

    DecP p;
    p.ctx = ctx; p.tgt = tgt;
    p.Wih0 = Wih0; p.Whh0 = Whh0; p.Wih1 = Wih1; p.Whh1 = Whh1;
    p.bih1 = bih1; p.bhh1 = bhh1; p.Wl = Wl; p.bl = bl;
    p.out = out;
    p.h1a = h1a; p.h1b = h1b; p.h2a = h2a; p.h2b = h2b;
    p.c1 = c1; p.c2 = c2; p.E = E;
    p.pm = pm; p.pl = pl; p.pacc = pacc; p.algn = algn;
    p.idx = idx; p.cnt = cnt; p.bar = bar;

    void* args[] = { &p };
    hipError_t err = hipLaunchCooperativeKernel((const void*)decoder_persist,
                                                dim3(256), dim3(512), args, 0, stream);
    if (err != hipSuccess) {
        (void)hipGetLastError();   // clear error state; run verified fallback path
        for (int t = 0; t < NT; ++t) {
            float* h1i = (t & 1) ? h1b : h1a;  float* h1o = (t & 1) ? h1a : h1b;
            float* h2i = (t & 1) ? h2b : h2a;  float* h2o = (t & 1) ? h2a : h2b;
            attn_fb<<<dim3(NCHF, NB), 256, 0, stream>>>(ctx, h2i, Wl, bl, pm, pl, pacc,
                                                        algn, cnt, idx, out, t);
            lstm0_fb<<<dim3(64, 8), 256, 0, stream>>>(algn, h1i, c1, E, idx, Wih0, Whh0, h1o);
            lstm1_fb<<<dim3(64, 8), 256, 0, stream>>>(h1o, h2i, c2, Wih1, Whh1, bih1, bhh1, h2o);
        }
        tail_fb<<<NB, 256, 0, stream>>>(h2a, Wl, bl, tgt, out);
    }
}